// Round 20
// baseline (264.882 us; speedup 1.0000x reference)
//
#include <hip/hip_runtime.h>
#include <hip/hip_bf16.h>
#include <stdint.h>

typedef __attribute__((ext_vector_type(4))) float f32x4;
typedef __attribute__((ext_vector_type(8))) short bf16x8;
typedef __attribute__((ext_vector_type(8))) unsigned short u16x8;
typedef __attribute__((ext_vector_type(4))) unsigned short u16x4;

#define NPIX 100352      // 32*56*56
#define CDIM 256
#define QKVN 768
#define HWDIM 56

__device__ __forceinline__ unsigned short f2bf(float f) {
  union { float f; unsigned int u; } cv; cv.f = f;
  unsigned int u = cv.u;
  unsigned int r = (u + 0x7FFFu + ((u >> 16) & 1u)) >> 16;
  return (unsigned short)r;
}
__device__ __forceinline__ float bf2f(unsigned short h) {
  union { unsigned int u; float f; } cv; cv.u = ((unsigned int)h) << 16;
  return cv.f;
}
// packed pair convert via official intrinsic (compiler emits v_cvt_pk_bf16_f32)
__device__ __forceinline__ unsigned pk2(float lo, float hi) {
  float2 a; a.x = lo; a.y = hi;
  __hip_bfloat162 h = __float22bfloat162_rn(a);
  union { __hip_bfloat162 h; unsigned u; } cv; cv.h = h;
  return cv.u;
}

// ---------------- merged prep: bias table (f32*log2e) + Wqkv + Wproj fragment tables ----------------
// blocks 0..511: bias_pre | 512..607: wqkv_pre | 608..639: wproj_pre
__global__ __launch_bounds__(256) void prep_kernel(
    const float* __restrict__ table, float* __restrict__ bt,
    const float* __restrict__ wq, unsigned short* __restrict__ wtab,
    const float* __restrict__ wp, unsigned short* __restrict__ wptab)
{
  const int bid = blockIdx.x;
  if (bid < 512) {
    int e = bid * 256 + threadIdx.x;             // 131072 total
    int r  = e & 3;
    int fr = (e >> 2) & 15;
    int q  = (e >> 6) & 3;
    int c2 = (e >> 8) & 3;
    int jf = (e >> 10) & 3;
    int h  = (e >> 12) & 7;
    int cls = (e >> 15) & 3;
    int j = jf * 16 + q * 4 + r;
    int i = c2 * 16 + fr;
    float v;
    if (j > 48 || i > 48) {
      v = -1e30f;
    } else {
      int bh = cls >> 1, bw = cls & 1;
      int iwi = i / 7, iwj = i % 7;
      int jwi = j / 7, jwj = j % 7;
      int ireg = (bh ? ((iwi < 4) ? 1 : 2) : 0) * 3 + (bw ? ((iwj < 4) ? 1 : 2) : 0);
      int jreg = (bh ? ((jwi < 4) ? 1 : 2) : 0) * 3 + (bw ? ((jwj < 4) ? 1 : 2) : 0);
      float m = (ireg == jreg) ? 0.f : -100.f;
      v = (table[((iwi - jwi + 6) * 13 + (iwj - jwj + 6)) * 8 + h] + m) * 1.44269504088896340f;
    }
    bt[e] = v;
  } else if (bid < 608) {
    int e8 = (bid - 512) * 256 + threadIdx.x;    // 24576 total
    int l = e8 & 63;
    int t1 = e8 >> 6;
    int wsel = t1 & 1;
    int ks = (t1 >> 1) & 7;
    int h = (t1 >> 4) & 7;
    int m = t1 >> 7;          // 0..2
    int row = m * 256 + h * 32 + wsel * 16 + (l & 15);
    int col = ks * 32 + (l >> 4) * 8;
    const float4* src = reinterpret_cast<const float4*>(wq + (size_t)row * 256 + col);
    float4 a = src[0], b = src[1];
    u16x8 r;
    r[0] = f2bf(a.x); r[1] = f2bf(a.y); r[2] = f2bf(a.z); r[3] = f2bf(a.w);
    r[4] = f2bf(b.x); r[5] = f2bf(b.y); r[6] = f2bf(b.z); r[7] = f2bf(b.w);
    *reinterpret_cast<u16x8*>(wtab + (size_t)e8 * 8) = r;
  } else {
    int e8 = (bid - 608) * 256 + threadIdx.x;    // 8192 total
    int l = e8 & 63;
    int t1 = e8 >> 6;
    int wsel = t1 & 1;
    int ks = (t1 >> 1) & 7;
    int h = (t1 >> 4) & 7;
    int row = h * 32 + wsel * 16 + (l & 15);
    int col = ks * 32 + (l >> 4) * 8;
    const float4* src = reinterpret_cast<const float4*>(wp + (size_t)row * 256 + col);
    float4 a = src[0], b = src[1];
    u16x8 r;
    r[0] = f2bf(a.x); r[1] = f2bf(a.y); r[2] = f2bf(a.z); r[3] = f2bf(a.w);
    r[4] = f2bf(b.x); r[5] = f2bf(b.y); r[6] = f2bf(b.z); r[7] = f2bf(b.w);
    *reinterpret_cast<u16x8*>(wptab + (size_t)e8 * 8) = r;
  }
}

// ---------------- persistent fused: QKV + attention + proj, 4 windows/block ----------------
// grid = 512 blocks (2/CU), 512 threads (8 waves = 8 heads)
__global__ __launch_bounds__(512, 2) void fused_attn(
    const float* __restrict__ x,              // [NPIX][256] fp32, pixel order
    const unsigned short* __restrict__ wtab,  // fragment-ordered Wqkv bf16
    const float* __restrict__ bqkv,           // [768]
    const float* __restrict__ btab,           // [4][8][4096] f32 (bias+mask)*log2e
    const unsigned short* __restrict__ wptab, // fragment-ordered Wproj bf16
    const float* __restrict__ bproj,          // [256]
    float* __restrict__ out)                  // [NPIX][256] fp32, pixel order
{
  const int bid = blockIdx.x;
  const int t = threadIdx.x;
  const int head = t >> 6;
  const int lane = t & 63;
  const int fr = lane & 15;
  const int q = lane >> 4;
  const int b = bid >> 4;                 // win = bid*4+g -> batch constant per block

  __shared__ unsigned short x_s[64 * 256];    // x window bf16, rows 49-63 ZERO; reused as out_s
  __shared__ unsigned short Vt[8][32 * 70];   // per head Vt[d][j], stride 70
  __shared__ int pix_s[64];

  unsigned short* VtW = Vt[head];
  const int srcA = ((q & 1) << 5) + fr;
  const int srcB = srcA + 16;
  const bool hi = (q >= 2);

  #define XS(row, bc) ((unsigned)((row) * 512 + (((bc)) ^ (((row) & 7) << 4))))

  #define PACK_MAT(accm, pkm)                                                          \
  { _Pragma("unroll") for (int d = 0; d < 2; ++d)                                      \
      _Pragma("unroll") for (int p2 = 0; p2 < 4; ++p2) {                               \
        pkm[d][p2][0] = pk2(accm[d][p2][0], accm[d][p2][1]);                           \
        pkm[d][p2][1] = pk2(accm[d][p2][2], accm[d][p2][3]);                           \
      } }

  #define BUILD_FRAG(pkm, p2, dst)                                                     \
  { unsigned a0 = (unsigned)__shfl((int)pkm[0][p2][0], srcA);                          \
    unsigned a1 = (unsigned)__shfl((int)pkm[0][p2][1], srcA);                          \
    unsigned a2 = (unsigned)__shfl((int)pkm[0][p2][0], srcB);                          \
    unsigned a3 = (unsigned)__shfl((int)pkm[0][p2][1], srcB);                          \
    unsigned b0 = (unsigned)__shfl((int)pkm[1][p2][0], srcA);                          \
    unsigned b1 = (unsigned)__shfl((int)pkm[1][p2][1], srcA);                          \
    unsigned b2 = (unsigned)__shfl((int)pkm[1][p2][0], srcB);                          \
    unsigned b3 = (unsigned)__shfl((int)pkm[1][p2][1], srcB);                          \
    union { unsigned u[4]; bf16x8 v; } uf;                                             \
    uf.u[0] = hi ? b0 : a0; uf.u[1] = hi ? b1 : a1;                                    \
    uf.u[2] = hi ? b2 : a2; uf.u[3] = hi ? b3 : a3;                                    \
    dst = uf.v; }

  #define XF_READS                                                                     \
    int bc = ks * 64 + q * 16;                                                         \
    bf16x8 xf0 = *reinterpret_cast<const bf16x8*>((const char*)x_s + XS(fr, bc));      \
    bf16x8 xf1 = *reinterpret_cast<const bf16x8*>((const char*)x_s + XS(16 + fr, bc)); \
    bf16x8 xf2 = *reinterpret_cast<const bf16x8*>((const char*)x_s + XS(32 + fr, bc)); \
    bf16x8 xf3 = *reinterpret_cast<const bf16x8*>((const char*)x_s + XS(48 + fr, bc));

  #pragma unroll 1
  for (int g = 0; g < 4; ++g) {
    const int win = (bid << 2) | g;
    const int gi = (win >> 3) & 7;
    const int gj = win & 7;

    if (g) __syncthreads();   // proj(g-1) done reading out_s/pix_s

    // pix map for proj (covered by the staging barrier below)
    if (t < 64) {
      int idx = (t < 49) ? t : 48;
      int wi = idx / 7, wj = idx - (idx / 7) * 7;
      int ph = gi * 7 + wi + 3; if (ph >= HWDIM) ph -= HWDIM;
      int pw = gj * 7 + wj + 3; if (pw >= HWDIM) pw -= HWDIM;
      pix_s[t] = (b * HWDIM + ph) * HWDIM + pw;
    }

    // ---- stage x window -> LDS bf16 (rows 49-63 zeroed; 4 uniform iterations) ----
    #pragma unroll
    for (int k = 0; k < 4; ++k) {
      int u = t + 512 * k;
      int pix = u >> 5, seg = u & 31;
      union { unsigned w[4]; u16x8 v; } r;
      if (pix < 49) {
        int wi = pix / 7, wj = pix - (pix / 7) * 7;
        int ph = gi * 7 + wi + 3; if (ph >= HWDIM) ph -= HWDIM;
        int pw = gj * 7 + wj + 3; if (pw >= HWDIM) pw -= HWDIM;
        int pabs = (b * HWDIM + ph) * HWDIM + pw;
        const float4* src = reinterpret_cast<const float4*>(x + (size_t)pabs * CDIM + seg * 8);
        float4 a = src[0], c = src[1];
        r.w[0] = pk2(a.x, a.y); r.w[1] = pk2(a.z, a.w);
        r.w[2] = pk2(c.x, c.y); r.w[3] = pk2(c.z, c.w);
      } else {
        r.w[0] = 0u; r.w[1] = 0u; r.w[2] = 0u; r.w[3] = 0u;
      }
      *reinterpret_cast<u16x8*>((char*)x_s + XS(pix, seg * 16)) = r.v;
    }
    __syncthreads();   // covers x_s AND pix_s

    const int cls = (((gi == 7) ? 1 : 0) << 1) | ((gj == 7) ? 1 : 0);
    const float* bth = btab + (((cls << 3) | head) << 12);

    unsigned pkk[2][4][2], pkq[2][4][2];

    // ---- pass V: compute V, scatter to Vt (acc dies into LDS) ----
    {
      f32x4 acc[2][4];
      #pragma unroll
      for (int d = 0; d < 2; ++d)
        #pragma unroll
        for (int p2 = 0; p2 < 4; ++p2)
          acc[d][p2] = (f32x4){0.f, 0.f, 0.f, 0.f};
      #pragma unroll
      for (int ks = 0; ks < 8; ++ks) {
        const unsigned short* wb = wtab + (size_t)((((2 * 8 + head) * 8 + ks) * 128 + lane) * 8);
        bf16x8 wf0 = *reinterpret_cast<const bf16x8*>(wb);
        bf16x8 wf1 = *reinterpret_cast<const bf16x8*>(wb + 512);
        XF_READS
        acc[0][0] = __builtin_amdgcn_mfma_f32_16x16x32_bf16(wf0, xf0, acc[0][0], 0, 0, 0);
        acc[0][1] = __builtin_amdgcn_mfma_f32_16x16x32_bf16(wf0, xf1, acc[0][1], 0, 0, 0);
        acc[0][2] = __builtin_amdgcn_mfma_f32_16x16x32_bf16(wf0, xf2, acc[0][2], 0, 0, 0);
        acc[0][3] = __builtin_amdgcn_mfma_f32_16x16x32_bf16(wf0, xf3, acc[0][3], 0, 0, 0);
        acc[1][0] = __builtin_amdgcn_mfma_f32_16x16x32_bf16(wf1, xf0, acc[1][0], 0, 0, 0);
        acc[1][1] = __builtin_amdgcn_mfma_f32_16x16x32_bf16(wf1, xf1, acc[1][1], 0, 0, 0);
        acc[1][2] = __builtin_amdgcn_mfma_f32_16x16x32_bf16(wf1, xf2, acc[1][2], 0, 0, 0);
        acc[1][3] = __builtin_amdgcn_mfma_f32_16x16x32_bf16(wf1, xf3, acc[1][3], 0, 0, 0);
      }
      #pragma unroll
      for (int d = 0; d < 2; ++d) {
        f32x4 bv = *reinterpret_cast<const f32x4*>(bqkv + 512 + head * 32 + d * 16 + q * 4);
        #pragma unroll
        for (int p2 = 0; p2 < 4; ++p2) {
          f32x4 v = acc[d][p2] + bv;
          #pragma unroll
          for (int r = 0; r < 4; ++r)
            VtW[(d * 16 + q * 4 + r) * 70 + p2 * 16 + fr] = f2bf(v[r]);
        }
      }
    }

    // ---- pass K+Q fused: one xf read feeds both weight sets ----
    {
      f32x4 acck[2][4], accq[2][4];
      #pragma unroll
      for (int d = 0; d < 2; ++d)
        #pragma unroll
        for (int p2 = 0; p2 < 4; ++p2) {
          acck[d][p2] = (f32x4){0.f, 0.f, 0.f, 0.f};
          accq[d][p2] = (f32x4){0.f, 0.f, 0.f, 0.f};
        }
      #pragma unroll
      for (int ks = 0; ks < 8; ++ks) {
        const unsigned short* wbK = wtab + (size_t)((((1 * 8 + head) * 8 + ks) * 128 + lane) * 8);
        const unsigned short* wbQ = wtab + (size_t)((((0 * 8 + head) * 8 + ks) * 128 + lane) * 8);
        bf16x8 wk0 = *reinterpret_cast<const bf16x8*>(wbK);
        bf16x8 wk1 = *reinterpret_cast<const bf16x8*>(wbK + 512);
        bf16x8 wq0 = *reinterpret_cast<const bf16x8*>(wbQ);
        bf16x8 wq1 = *reinterpret_cast<const bf16x8*>(wbQ + 512);
        XF_READS
        acck[0][0] = __builtin_amdgcn_mfma_f32_16x16x32_bf16(wk0, xf0, acck[0][0], 0, 0, 0);
        acck[0][1] = __builtin_amdgcn_mfma_f32_16x16x32_bf16(wk0, xf1, acck[0][1], 0, 0, 0);
        acck[0][2] = __builtin_amdgcn_mfma_f32_16x16x32_bf16(wk0, xf2, acck[0][2], 0, 0, 0);
        acck[0][3] = __builtin_amdgcn_mfma_f32_16x16x32_bf16(wk0, xf3, acck[0][3], 0, 0, 0);
        acck[1][0] = __builtin_amdgcn_mfma_f32_16x16x32_bf16(wk1, xf0, acck[1][0], 0, 0, 0);
        acck[1][1] = __builtin_amdgcn_mfma_f32_16x16x32_bf16(wk1, xf1, acck[1][1], 0, 0, 0);
        acck[1][2] = __builtin_amdgcn_mfma_f32_16x16x32_bf16(wk1, xf2, acck[1][2], 0, 0, 0);
        acck[1][3] = __builtin_amdgcn_mfma_f32_16x16x32_bf16(wk1, xf3, acck[1][3], 0, 0, 0);
        accq[0][0] = __builtin_amdgcn_mfma_f32_16x16x32_bf16(wq0, xf0, accq[0][0], 0, 0, 0);
        accq[0][1] = __builtin_amdgcn_mfma_f32_16x16x32_bf16(wq0, xf1, accq[0][1], 0, 0, 0);
        accq[0][2] = __builtin_amdgcn_mfma_f32_16x16x32_bf16(wq0, xf2, accq[0][2], 0, 0, 0);
        accq[0][3] = __builtin_amdgcn_mfma_f32_16x16x32_bf16(wq0, xf3, accq[0][3], 0, 0, 0);
        accq[1][0] = __builtin_amdgcn_mfma_f32_16x16x32_bf16(wq1, xf0, accq[1][0], 0, 0, 0);
        accq[1][1] = __builtin_amdgcn_mfma_f32_16x16x32_bf16(wq1, xf1, accq[1][1], 0, 0, 0);
        accq[1][2] = __builtin_amdgcn_mfma_f32_16x16x32_bf16(wq1, xf2, accq[1][2], 0, 0, 0);
        accq[1][3] = __builtin_amdgcn_mfma_f32_16x16x32_bf16(wq1, xf3, accq[1][3], 0, 0, 0);
      }
      #pragma unroll
      for (int d = 0; d < 2; ++d) {
        f32x4 bvk = *reinterpret_cast<const f32x4*>(bqkv + 256 + head * 32 + d * 16 + q * 4);
        f32x4 bvq = *reinterpret_cast<const f32x4*>(bqkv +       head * 32 + d * 16 + q * 4);
        #pragma unroll
        for (int p2 = 0; p2 < 4; ++p2) {
          acck[d][p2] += bvk;
          accq[d][p2] += bvq;
        }
      }
      PACK_MAT(acck, pkk);
      PACK_MAT(accq, pkq);
    }

    bf16x8 qf[4];
    BUILD_FRAG(pkq, 0, qf[0]); BUILD_FRAG(pkq, 1, qf[1]);
    BUILD_FRAG(pkq, 2, qf[2]); BUILD_FRAG(pkq, 3, qf[3]);

    // ---- S^T + softmax (base-2: scale and bias pre-multiplied by log2e) ----
    const float scale = 0.17677669529663687f * 1.44269504088896340f;
    f32x4 aw[2][4];
    #pragma unroll
    for (int c2 = 0; c2 < 4; ++c2)
      aw[0][c2] = *reinterpret_cast<const f32x4*>(bth + (c2 << 8) + (q << 6) + (fr << 2));
    float colsum[4] = {0.f, 0.f, 0.f, 0.f};
    unsigned pk[4][4][2];
    #pragma unroll
    for (int jf = 0; jf < 4; ++jf) {
      bf16x8 kfj;
      BUILD_FRAG(pkk, jf, kfj);
      f32x4 sacc[4];
      #pragma unroll
      for (int c2 = 0; c2 < 4; ++c2) {
        f32x4 z = {0.f, 0.f, 0.f, 0.f};
        sacc[c2] = __builtin_amdgcn_mfma_f32_16x16x32_bf16(kfj, qf[c2], z, 0, 0, 0);
      }
      if (jf < 3) {
        #pragma unroll
        for (int c2 = 0; c2 < 4; ++c2)
          aw[(jf + 1) & 1][c2] = *reinterpret_cast<const f32x4*>(
              bth + (((jf + 1) * 4 + c2) << 8) + (q << 6) + (fr << 2));
      }
      #pragma unroll
      for (int c2 = 0; c2 < 4; ++c2) {
        float ev[4];
        #pragma unroll
        for (int r = 0; r < 4; ++r) {
          float val = fmaf(sacc[c2][r], scale, aw[jf & 1][c2][r]);
          ev[r] = __builtin_amdgcn_exp2f(val);
          colsum[c2] += ev[r];
        }
        pk[jf][c2][0] = pk2(ev[0], ev[1]);
        pk[jf][c2][1] = pk2(ev[2], ev[3]);
      }
    }
    float rinv[4];
    #pragma unroll
    for (int c2 = 0; c2 < 4; ++c2) {
      float s = colsum[c2];
      s += __shfl_xor(s, 16);
      s += __shfl_xor(s, 32);
      rinv[c2] = 1.0f / s;
    }

    // ---- PV: attnT[d][i] = sum_j Vt[d][j] * P^T[j][i] ----
    f32x4 outT[2][4] = {};
    #pragma unroll
    for (int kb = 0; kb < 2; ++kb) {
      bf16x8 vf0 = *reinterpret_cast<const bf16x8*>(&VtW[(fr)      * 70 + kb * 32 + q * 8]);
      bf16x8 vf1 = *reinterpret_cast<const bf16x8*>(&VtW[(16 + fr) * 70 + kb * 32 + q * 8]);
      #pragma unroll
      for (int c2 = 0; c2 < 4; ++c2) {
        bf16x8 pf;
        {
          unsigned a0 = (unsigned)__shfl((int)pk[2 * kb][c2][0], srcA);
          unsigned a1 = (unsigned)__shfl((int)pk[2 * kb][c2][1], srcA);
          unsigned a2 = (unsigned)__shfl((int)pk[2 * kb][c2][0], srcB);
          unsigned a3 = (unsigned)__shfl((int)pk[2 * kb][c2][1], srcB);
          unsigned b0 = (unsigned)__shfl((int)pk[2 * kb + 1][c2][0], srcA);
          unsigned b1 = (unsigned)__shfl((int)pk[2 * kb + 1][c2][1], srcA);
          unsigned b2 = (unsigned)__shfl((int)pk[2 * kb + 1][c2][0], srcB);
          unsigned b3 = (unsigned)__shfl((int)pk[2 * kb + 1][c2][1], srcB);
          union { unsigned u[4]; bf16x8 v; } pfv;
          pfv.u[0] = hi ? b0 : a0;
          pfv.u[1] = hi ? b1 : a1;
          pfv.u[2] = hi ? b2 : a2;
          pfv.u[3] = hi ? b3 : a3;
          pf = pfv.v;
        }
        outT[0][c2] = __builtin_amdgcn_mfma_f32_16x16x32_bf16(vf0, pf, outT[0][c2], 0, 0, 0);
        outT[1][c2] = __builtin_amdgcn_mfma_f32_16x16x32_bf16(vf1, pf, outT[1][c2], 0, 0, 0);
      }
    }

    // ---- stage attnout in LDS (reuse x_s region rows 0-48; rows 49-63 stay zero) ----
    unsigned short* out_s = x_s;
    __syncthreads();   // all waves done reading x_s / own Vt
    #pragma unroll
    for (int c2 = 0; c2 < 4; ++c2) {
      int i = c2 * 16 + fr;
      if (i < 49) {
        float rv = rinv[c2];
        #pragma unroll
        for (int nt = 0; nt < 2; ++nt) {
          f32x4 o = outT[nt][c2];
          union { unsigned w[2]; u16x4 v; } pd;
          pd.w[0] = pk2(o[0] * rv, o[1] * rv);
          pd.w[1] = pk2(o[2] * rv, o[3] * rv);
          *reinterpret_cast<u16x4*>((char*)out_s + XS(i, head * 64 + nt * 32 + q * 8)) = pd.v;
        }
      }
    }
    __syncthreads();   // out_s complete (proj consumes all heads' columns)

    // ---- fused proj: D[pix][dim] = attnout(49x256) x Wproj^T slice (32 cols/head) ----
    {
      f32x4 pacc[2][4];   // [wsel][p2]
      #pragma unroll
      for (int w = 0; w < 2; ++w)
        #pragma unroll
        for (int p2 = 0; p2 < 4; ++p2)
          pacc[w][p2] = (f32x4){0.f, 0.f, 0.f, 0.f};
      #pragma unroll
      for (int ks = 0; ks < 8; ++ks) {
        const unsigned short* wb = wptab + (size_t)((((head * 8 + ks) * 2) * 64 + lane) * 8);
        bf16x8 wp0 = *reinterpret_cast<const bf16x8*>(wb);
        bf16x8 wp1 = *reinterpret_cast<const bf16x8*>(wb + 512);
        int bc = ks * 64 + q * 16;
        bf16x8 of0 = *reinterpret_cast<const bf16x8*>((const char*)x_s + XS(fr, bc));
        bf16x8 of1 = *reinterpret_cast<const bf16x8*>((const char*)x_s + XS(16 + fr, bc));
        bf16x8 of2 = *reinterpret_cast<const bf16x8*>((const char*)x_s + XS(32 + fr, bc));
        bf16x8 of3 = *reinterpret_cast<const bf16x8*>((const char*)x_s + XS(48 + fr, bc));
        pacc[0][0] = __builtin_amdgcn_mfma_f32_16x16x32_bf16(of0, wp0, pacc[0][0], 0, 0, 0);
        pacc[0][1] = __builtin_amdgcn_mfma_f32_16x16x32_bf16(of1, wp0, pacc[0][1], 0, 0, 0);
        pacc[0][2] = __builtin_amdgcn_mfma_f32_16x16x32_bf16(of2, wp0, pacc[0][2], 0, 0, 0);
        pacc[0][3] = __builtin_amdgcn_mfma_f32_16x16x32_bf16(of3, wp0, pacc[0][3], 0, 0, 0);
        pacc[1][0] = __builtin_amdgcn_mfma_f32_16x16x32_bf16(of0, wp1, pacc[1][0], 0, 0, 0);
        pacc[1][1] = __builtin_amdgcn_mfma_f32_16x16x32_bf16(of1, wp1, pacc[1][1], 0, 0, 0);
        pacc[1][2] = __builtin_amdgcn_mfma_f32_16x16x32_bf16(of2, wp1, pacc[1][2], 0, 0, 0);
        pacc[1][3] = __builtin_amdgcn_mfma_f32_16x16x32_bf16(of3, wp1, pacc[1][3], 0, 0, 0);
      }
      float bb0 = bproj[head * 32 + fr];
      float bb1 = bproj[head * 32 + 16 + fr];
      #pragma unroll
      for (int p2 = 0; p2 < 4; ++p2) {
        #pragma unroll
        for (int r = 0; r < 4; ++r) {
          int pix = p2 * 16 + q * 4 + r;
          if (pix < 49) {
            float* op = out + (size_t)pix_s[pix] * CDIM + head * 32 + fr;
            op[0]  = pacc[0][p2][r] + bb0;
            op[16] = pacc[1][p2][r] + bb1;
          }
        }
      }
    }
  }
  #undef PACK_MAT
  #undef BUILD_FRAG
  #undef XF_READS
  #undef XS
}

// ---------------- launch ----------------
extern "C" void kernel_launch(void* const* d_in, const int* in_sizes, int n_in,
                              void* d_out, int out_size, void* d_ws, size_t ws_size,
                              hipStream_t stream) {
  const float* x      = (const float*)d_in[0];
  const float* qkv_w  = (const float*)d_in[1];
  const float* qkv_b  = (const float*)d_in[2];
  const float* proj_w = (const float*)d_in[3];
  const float* proj_b = (const float*)d_in[4];
  const float* table  = (const float*)d_in[5];

  char* ws = (char*)d_ws;
  float*          btab  = (float*)ws;                        // 524,288 B
  unsigned short* wtab  = (unsigned short*)(ws + 524288);    // 393,216 B
  unsigned short* wptab = (unsigned short*)(ws + 917504);    // 131,072 B

  prep_kernel<<<640, 256, 0, stream>>>(table, btab, qkv_w, wtab, proj_w, wptab);

  fused_attn<<<512, 512, 0, stream>>>(x, wtab, qkv_b, btab, wptab, proj_b,
                                      (float*)d_out);
}

// Round 21
// 138.896 us; speedup vs baseline: 1.9071x; 1.9071x over previous
//
#include <hip/hip_runtime.h>
#include <hip/hip_bf16.h>
#include <stdint.h>

typedef __attribute__((ext_vector_type(4))) float f32x4;
typedef __attribute__((ext_vector_type(8))) short bf16x8;
typedef __attribute__((ext_vector_type(8))) unsigned short u16x8;
typedef __attribute__((ext_vector_type(4))) unsigned short u16x4;

#define NPIX 100352      // 32*56*56
#define CDIM 256
#define QKVN 768
#define HWDIM 56

__device__ __forceinline__ unsigned short f2bf(float f) {
  union { float f; unsigned int u; } cv; cv.f = f;
  unsigned int u = cv.u;
  unsigned int r = (u + 0x7FFFu + ((u >> 16) & 1u)) >> 16;
  return (unsigned short)r;
}
__device__ __forceinline__ float bf2f(unsigned short h) {
  union { unsigned int u; float f; } cv; cv.u = ((unsigned int)h) << 16;
  return cv.f;
}
// packed pair convert via official intrinsic (compiler emits v_cvt_pk_bf16_f32)
__device__ __forceinline__ unsigned pk2(float lo, float hi) {
  float2 a; a.x = lo; a.y = hi;
  __hip_bfloat162 h = __float22bfloat162_rn(a);
  union { __hip_bfloat162 h; unsigned u; } cv; cv.h = h;
  return cv.u;
}

// ---------------- merged prep: bias table (f32*log2e) + Wqkv + Wproj fragment tables ----------------
// blocks 0..511: bias_pre | 512..607: wqkv_pre | 608..639: wproj_pre
__global__ __launch_bounds__(256) void prep_kernel(
    const float* __restrict__ table, float* __restrict__ bt,
    const float* __restrict__ wq, unsigned short* __restrict__ wtab,
    const float* __restrict__ wp, unsigned short* __restrict__ wptab)
{
  const int bid = blockIdx.x;
  if (bid < 512) {
    int e = bid * 256 + threadIdx.x;             // 131072 total
    int r  = e & 3;
    int fr = (e >> 2) & 15;
    int q  = (e >> 6) & 3;
    int c2 = (e >> 8) & 3;
    int jf = (e >> 10) & 3;
    int h  = (e >> 12) & 7;
    int cls = (e >> 15) & 3;
    int j = jf * 16 + q * 4 + r;
    int i = c2 * 16 + fr;
    float v;
    if (j > 48 || i > 48) {
      v = -1e30f;
    } else {
      int bh = cls >> 1, bw = cls & 1;
      int iwi = i / 7, iwj = i % 7;
      int jwi = j / 7, jwj = j % 7;
      int ireg = (bh ? ((iwi < 4) ? 1 : 2) : 0) * 3 + (bw ? ((iwj < 4) ? 1 : 2) : 0);
      int jreg = (bh ? ((jwi < 4) ? 1 : 2) : 0) * 3 + (bw ? ((jwj < 4) ? 1 : 2) : 0);
      float m = (ireg == jreg) ? 0.f : -100.f;
      v = (table[((iwi - jwi + 6) * 13 + (iwj - jwj + 6)) * 8 + h] + m) * 1.44269504088896340f;
    }
    bt[e] = v;
  } else if (bid < 608) {
    int e8 = (bid - 512) * 256 + threadIdx.x;    // 24576 total
    int l = e8 & 63;
    int t1 = e8 >> 6;
    int wsel = t1 & 1;
    int ks = (t1 >> 1) & 7;
    int h = (t1 >> 4) & 7;
    int m = t1 >> 7;          // 0..2
    int row = m * 256 + h * 32 + wsel * 16 + (l & 15);
    int col = ks * 32 + (l >> 4) * 8;
    const float4* src = reinterpret_cast<const float4*>(wq + (size_t)row * 256 + col);
    float4 a = src[0], b = src[1];
    u16x8 r;
    r[0] = f2bf(a.x); r[1] = f2bf(a.y); r[2] = f2bf(a.z); r[3] = f2bf(a.w);
    r[4] = f2bf(b.x); r[5] = f2bf(b.y); r[6] = f2bf(b.z); r[7] = f2bf(b.w);
    *reinterpret_cast<u16x8*>(wtab + (size_t)e8 * 8) = r;
  } else {
    int e8 = (bid - 608) * 256 + threadIdx.x;    // 8192 total
    int l = e8 & 63;
    int t1 = e8 >> 6;
    int wsel = t1 & 1;
    int ks = (t1 >> 1) & 7;
    int h = (t1 >> 4) & 7;
    int row = h * 32 + wsel * 16 + (l & 15);
    int col = ks * 32 + (l >> 4) * 8;
    const float4* src = reinterpret_cast<const float4*>(wp + (size_t)row * 256 + col);
    float4 a = src[0], b = src[1];
    u16x8 r;
    r[0] = f2bf(a.x); r[1] = f2bf(a.y); r[2] = f2bf(a.z); r[3] = f2bf(a.w);
    r[4] = f2bf(b.x); r[5] = f2bf(b.y); r[6] = f2bf(b.z); r[7] = f2bf(b.w);
    *reinterpret_cast<u16x8*>(wptab + (size_t)e8 * 8) = r;
  }
}

// ---------------- fully fused: QKV GEMM + shifted-window attention + proj GEMM ----------------
// block = window (512 threads, 8 waves = 8 heads); 2 blocks/CU (LDS-limited)
__global__ __launch_bounds__(512, 2) void fused_attn(
    const float* __restrict__ x,              // [NPIX][256] fp32, pixel order
    const unsigned short* __restrict__ wtab,  // fragment-ordered Wqkv bf16
    const float* __restrict__ bqkv,           // [768]
    const float* __restrict__ btab,           // [4][8][4096] f32 (bias+mask)*log2e
    const unsigned short* __restrict__ wptab, // fragment-ordered Wproj bf16
    const float* __restrict__ bproj,          // [256]
    float* __restrict__ out)                  // [NPIX][256] fp32, pixel order
{
  const int win = blockIdx.x;
  const int b = win >> 6;
  const int gi = (win >> 3) & 7;
  const int gj = win & 7;
  const int t = threadIdx.x;
  const int head = t >> 6;
  const int lane = t & 63;
  const int fr = lane & 15;
  const int q = lane >> 4;

  __shared__ unsigned short x_s[64 * 256];    // x window bf16, rows 49-63 ZERO; reused as out_s
  __shared__ unsigned short Vt[8][32 * 70];   // per head Vt[d][j], stride 70
  __shared__ int pix_s[64];

  // pix map for proj (covered by the staging barrier below)
  if (t < 64) {
    int idx = (t < 49) ? t : 48;
    int wi = idx / 7, wj = idx - (idx / 7) * 7;
    int ph = gi * 7 + wi + 3; if (ph >= HWDIM) ph -= HWDIM;
    int pw = gj * 7 + wj + 3; if (pw >= HWDIM) pw -= HWDIM;
    pix_s[t] = (b * HWDIM + ph) * HWDIM + pw;
  }

  // byte offset into x_s/out_s for (row, bytecol): XOR swizzle -> ~2-way banks
  #define XS(row, bc) ((unsigned)((row) * 512 + (((bc)) ^ (((row) & 7) << 4))))

  // ---- stage x window -> LDS bf16 (rows 49-63 zeroed; 4 uniform iterations) ----
  #pragma unroll
  for (int k = 0; k < 4; ++k) {
    int u = t + 512 * k;
    int pix = u >> 5, seg = u & 31;
    union { unsigned w[4]; u16x8 v; } r;
    if (pix < 49) {
      int wi = pix / 7, wj = pix - (pix / 7) * 7;
      int ph = gi * 7 + wi + 3; if (ph >= HWDIM) ph -= HWDIM;
      int pw = gj * 7 + wj + 3; if (pw >= HWDIM) pw -= HWDIM;
      int pabs = (b * HWDIM + ph) * HWDIM + pw;
      const float4* src = reinterpret_cast<const float4*>(x + (size_t)pabs * CDIM + seg * 8);
      float4 a = src[0], c = src[1];
      r.w[0] = pk2(a.x, a.y); r.w[1] = pk2(a.z, a.w);
      r.w[2] = pk2(c.x, c.y); r.w[3] = pk2(c.z, c.w);
    } else {
      r.w[0] = 0u; r.w[1] = 0u; r.w[2] = 0u; r.w[3] = 0u;
    }
    *reinterpret_cast<u16x8*>((char*)x_s + XS(pix, seg * 16)) = r.v;
  }
  __syncthreads();   // covers x_s AND pix_s

  const int cls = (((gi == 7) ? 1 : 0) << 1) | ((gj == 7) ? 1 : 0);
  const float* bth = btab + (((cls << 3) | head) << 12);
  unsigned short* VtW = Vt[head];
  const int srcA = ((q & 1) << 5) + fr;
  const int srcB = srcA + 16;
  const bool hi = (q >= 2);

  #define PACK_MAT(accm, pkm)                                                          \
  { _Pragma("unroll") for (int d = 0; d < 2; ++d)                                      \
      _Pragma("unroll") for (int p2 = 0; p2 < 4; ++p2) {                               \
        pkm[d][p2][0] = pk2(accm[d][p2][0], accm[d][p2][1]);                           \
        pkm[d][p2][1] = pk2(accm[d][p2][2], accm[d][p2][3]);                           \
      } }

  #define BUILD_FRAG(pkm, p2, dst)                                                     \
  { unsigned a0 = (unsigned)__shfl((int)pkm[0][p2][0], srcA);                          \
    unsigned a1 = (unsigned)__shfl((int)pkm[0][p2][1], srcA);                          \
    unsigned a2 = (unsigned)__shfl((int)pkm[0][p2][0], srcB);                          \
    unsigned a3 = (unsigned)__shfl((int)pkm[0][p2][1], srcB);                          \
    unsigned b0 = (unsigned)__shfl((int)pkm[1][p2][0], srcA);                          \
    unsigned b1 = (unsigned)__shfl((int)pkm[1][p2][1], srcA);                          \
    unsigned b2 = (unsigned)__shfl((int)pkm[1][p2][0], srcB);                          \
    unsigned b3 = (unsigned)__shfl((int)pkm[1][p2][1], srcB);                          \
    union { unsigned u[4]; bf16x8 v; } uf;                                             \
    uf.u[0] = hi ? b0 : a0; uf.u[1] = hi ? b1 : a1;                                    \
    uf.u[2] = hi ? b2 : a2; uf.u[3] = hi ? b3 : a3;                                    \
    dst = uf.v; }

  #define XF_READS                                                                     \
    int bc = ks * 64 + q * 16;                                                         \
    bf16x8 xf0 = *reinterpret_cast<const bf16x8*>((const char*)x_s + XS(fr, bc));      \
    bf16x8 xf1 = *reinterpret_cast<const bf16x8*>((const char*)x_s + XS(16 + fr, bc)); \
    bf16x8 xf2 = *reinterpret_cast<const bf16x8*>((const char*)x_s + XS(32 + fr, bc)); \
    bf16x8 xf3 = *reinterpret_cast<const bf16x8*>((const char*)x_s + XS(48 + fr, bc));

  unsigned pkk[2][4][2], pkq[2][4][2];

  // ---- pass V: compute V, scatter to Vt (acc dies into LDS) ----
  {
    f32x4 acc[2][4];
    #pragma unroll
    for (int d = 0; d < 2; ++d)
      #pragma unroll
      for (int p2 = 0; p2 < 4; ++p2)
        acc[d][p2] = (f32x4){0.f, 0.f, 0.f, 0.f};
    #pragma unroll
    for (int ks = 0; ks < 8; ++ks) {
      const unsigned short* wb = wtab + (size_t)((((2 * 8 + head) * 8 + ks) * 128 + lane) * 8);
      bf16x8 wf0 = *reinterpret_cast<const bf16x8*>(wb);
      bf16x8 wf1 = *reinterpret_cast<const bf16x8*>(wb + 512);
      XF_READS
      acc[0][0] = __builtin_amdgcn_mfma_f32_16x16x32_bf16(wf0, xf0, acc[0][0], 0, 0, 0);
      acc[0][1] = __builtin_amdgcn_mfma_f32_16x16x32_bf16(wf0, xf1, acc[0][1], 0, 0, 0);
      acc[0][2] = __builtin_amdgcn_mfma_f32_16x16x32_bf16(wf0, xf2, acc[0][2], 0, 0, 0);
      acc[0][3] = __builtin_amdgcn_mfma_f32_16x16x32_bf16(wf0, xf3, acc[0][3], 0, 0, 0);
      acc[1][0] = __builtin_amdgcn_mfma_f32_16x16x32_bf16(wf1, xf0, acc[1][0], 0, 0, 0);
      acc[1][1] = __builtin_amdgcn_mfma_f32_16x16x32_bf16(wf1, xf1, acc[1][1], 0, 0, 0);
      acc[1][2] = __builtin_amdgcn_mfma_f32_16x16x32_bf16(wf1, xf2, acc[1][2], 0, 0, 0);
      acc[1][3] = __builtin_amdgcn_mfma_f32_16x16x32_bf16(wf1, xf3, acc[1][3], 0, 0, 0);
    }
    #pragma unroll
    for (int d = 0; d < 2; ++d) {
      f32x4 bv = *reinterpret_cast<const f32x4*>(bqkv + 512 + head * 32 + d * 16 + q * 4);
      #pragma unroll
      for (int p2 = 0; p2 < 4; ++p2) {
        f32x4 v = acc[d][p2] + bv;
        #pragma unroll
        for (int r = 0; r < 4; ++r)
          VtW[(d * 16 + q * 4 + r) * 70 + p2 * 16 + fr] = f2bf(v[r]);
      }
    }
  }

  // ---- pass K+Q fused: one xf read feeds both weight sets ----
  {
    f32x4 acck[2][4], accq[2][4];
    #pragma unroll
    for (int d = 0; d < 2; ++d)
      #pragma unroll
      for (int p2 = 0; p2 < 4; ++p2) {
        acck[d][p2] = (f32x4){0.f, 0.f, 0.f, 0.f};
        accq[d][p2] = (f32x4){0.f, 0.f, 0.f, 0.f};
      }
    #pragma unroll
    for (int ks = 0; ks < 8; ++ks) {
      const unsigned short* wbK = wtab + (size_t)((((1 * 8 + head) * 8 + ks) * 128 + lane) * 8);
      const unsigned short* wbQ = wtab + (size_t)((((0 * 8 + head) * 8 + ks) * 128 + lane) * 8);
      bf16x8 wk0 = *reinterpret_cast<const bf16x8*>(wbK);
      bf16x8 wk1 = *reinterpret_cast<const bf16x8*>(wbK + 512);
      bf16x8 wq0 = *reinterpret_cast<const bf16x8*>(wbQ);
      bf16x8 wq1 = *reinterpret_cast<const bf16x8*>(wbQ + 512);
      XF_READS
      acck[0][0] = __builtin_amdgcn_mfma_f32_16x16x32_bf16(wk0, xf0, acck[0][0], 0, 0, 0);
      acck[0][1] = __builtin_amdgcn_mfma_f32_16x16x32_bf16(wk0, xf1, acck[0][1], 0, 0, 0);
      acck[0][2] = __builtin_amdgcn_mfma_f32_16x16x32_bf16(wk0, xf2, acck[0][2], 0, 0, 0);
      acck[0][3] = __builtin_amdgcn_mfma_f32_16x16x32_bf16(wk0, xf3, acck[0][3], 0, 0, 0);
      acck[1][0] = __builtin_amdgcn_mfma_f32_16x16x32_bf16(wk1, xf0, acck[1][0], 0, 0, 0);
      acck[1][1] = __builtin_amdgcn_mfma_f32_16x16x32_bf16(wk1, xf1, acck[1][1], 0, 0, 0);
      acck[1][2] = __builtin_amdgcn_mfma_f32_16x16x32_bf16(wk1, xf2, acck[1][2], 0, 0, 0);
      acck[1][3] = __builtin_amdgcn_mfma_f32_16x16x32_bf16(wk1, xf3, acck[1][3], 0, 0, 0);
      accq[0][0] = __builtin_amdgcn_mfma_f32_16x16x32_bf16(wq0, xf0, accq[0][0], 0, 0, 0);
      accq[0][1] = __builtin_amdgcn_mfma_f32_16x16x32_bf16(wq0, xf1, accq[0][1], 0, 0, 0);
      accq[0][2] = __builtin_amdgcn_mfma_f32_16x16x32_bf16(wq0, xf2, accq[0][2], 0, 0, 0);
      accq[0][3] = __builtin_amdgcn_mfma_f32_16x16x32_bf16(wq0, xf3, accq[0][3], 0, 0, 0);
      accq[1][0] = __builtin_amdgcn_mfma_f32_16x16x32_bf16(wq1, xf0, accq[1][0], 0, 0, 0);
      accq[1][1] = __builtin_amdgcn_mfma_f32_16x16x32_bf16(wq1, xf1, accq[1][1], 0, 0, 0);
      accq[1][2] = __builtin_amdgcn_mfma_f32_16x16x32_bf16(wq1, xf2, accq[1][2], 0, 0, 0);
      accq[1][3] = __builtin_amdgcn_mfma_f32_16x16x32_bf16(wq1, xf3, accq[1][3], 0, 0, 0);
    }
    #pragma unroll
    for (int d = 0; d < 2; ++d) {
      f32x4 bvk = *reinterpret_cast<const f32x4*>(bqkv + 256 + head * 32 + d * 16 + q * 4);
      f32x4 bvq = *reinterpret_cast<const f32x4*>(bqkv +       head * 32 + d * 16 + q * 4);
      #pragma unroll
      for (int p2 = 0; p2 < 4; ++p2) {
        acck[d][p2] += bvk;
        accq[d][p2] += bvq;
      }
    }
    PACK_MAT(acck, pkk);
    PACK_MAT(accq, pkq);
  }

  bf16x8 qf[4];
  BUILD_FRAG(pkq, 0, qf[0]); BUILD_FRAG(pkq, 1, qf[1]);
  BUILD_FRAG(pkq, 2, qf[2]); BUILD_FRAG(pkq, 3, qf[3]);

  // ---- S^T + softmax (base-2: scale and bias pre-multiplied by log2e) ----
  const float scale = 0.17677669529663687f * 1.44269504088896340f;
  f32x4 aw[2][4];
  #pragma unroll
  for (int c2 = 0; c2 < 4; ++c2)
    aw[0][c2] = *reinterpret_cast<const f32x4*>(bth + (c2 << 8) + (q << 6) + (fr << 2));
  float colsum[4] = {0.f, 0.f, 0.f, 0.f};
  unsigned pk[4][4][2];
  #pragma unroll
  for (int jf = 0; jf < 4; ++jf) {
    bf16x8 kfj;
    BUILD_FRAG(pkk, jf, kfj);
    f32x4 sacc[4];
    #pragma unroll
    for (int c2 = 0; c2 < 4; ++c2) {
      f32x4 z = {0.f, 0.f, 0.f, 0.f};
      sacc[c2] = __builtin_amdgcn_mfma_f32_16x16x32_bf16(kfj, qf[c2], z, 0, 0, 0);
    }
    if (jf < 3) {
      #pragma unroll
      for (int c2 = 0; c2 < 4; ++c2)
        aw[(jf + 1) & 1][c2] = *reinterpret_cast<const f32x4*>(
            bth + (((jf + 1) * 4 + c2) << 8) + (q << 6) + (fr << 2));
    }
    #pragma unroll
    for (int c2 = 0; c2 < 4; ++c2) {
      float ev[4];
      #pragma unroll
      for (int r = 0; r < 4; ++r) {
        float val = fmaf(sacc[c2][r], scale, aw[jf & 1][c2][r]);
        ev[r] = __builtin_amdgcn_exp2f(val);
        colsum[c2] += ev[r];
      }
      pk[jf][c2][0] = pk2(ev[0], ev[1]);
      pk[jf][c2][1] = pk2(ev[2], ev[3]);
    }
  }
  float rinv[4];
  #pragma unroll
  for (int c2 = 0; c2 < 4; ++c2) {
    float s = colsum[c2];
    s += __shfl_xor(s, 16);
    s += __shfl_xor(s, 32);
    rinv[c2] = 1.0f / s;
  }

  // ---- PV: attnT[d][i] = sum_j Vt[d][j] * P^T[j][i] ----
  f32x4 outT[2][4] = {};
  #pragma unroll
  for (int kb = 0; kb < 2; ++kb) {
    bf16x8 vf0 = *reinterpret_cast<const bf16x8*>(&VtW[(fr)      * 70 + kb * 32 + q * 8]);
    bf16x8 vf1 = *reinterpret_cast<const bf16x8*>(&VtW[(16 + fr) * 70 + kb * 32 + q * 8]);
    #pragma unroll
    for (int c2 = 0; c2 < 4; ++c2) {
      bf16x8 pf;
      {
        unsigned a0 = (unsigned)__shfl((int)pk[2 * kb][c2][0], srcA);
        unsigned a1 = (unsigned)__shfl((int)pk[2 * kb][c2][1], srcA);
        unsigned a2 = (unsigned)__shfl((int)pk[2 * kb][c2][0], srcB);
        unsigned a3 = (unsigned)__shfl((int)pk[2 * kb][c2][1], srcB);
        unsigned b0 = (unsigned)__shfl((int)pk[2 * kb + 1][c2][0], srcA);
        unsigned b1 = (unsigned)__shfl((int)pk[2 * kb + 1][c2][1], srcA);
        unsigned b2 = (unsigned)__shfl((int)pk[2 * kb + 1][c2][0], srcB);
        unsigned b3 = (unsigned)__shfl((int)pk[2 * kb + 1][c2][1], srcB);
        union { unsigned u[4]; bf16x8 v; } pfv;
        pfv.u[0] = hi ? b0 : a0;
        pfv.u[1] = hi ? b1 : a1;
        pfv.u[2] = hi ? b2 : a2;
        pfv.u[3] = hi ? b3 : a3;
        pf = pfv.v;
      }
      outT[0][c2] = __builtin_amdgcn_mfma_f32_16x16x32_bf16(vf0, pf, outT[0][c2], 0, 0, 0);
      outT[1][c2] = __builtin_amdgcn_mfma_f32_16x16x32_bf16(vf1, pf, outT[1][c2], 0, 0, 0);
    }
  }

  // ---- stage attnout in LDS (reuse x_s region rows 0-48; rows 49-63 stay zero) ----
  unsigned short* out_s = x_s;
  __syncthreads();   // all waves done reading x_s / own Vt
  #pragma unroll
  for (int c2 = 0; c2 < 4; ++c2) {
    int i = c2 * 16 + fr;
    if (i < 49) {
      float rv = rinv[c2];
      #pragma unroll
      for (int nt = 0; nt < 2; ++nt) {
        f32x4 o = outT[nt][c2];
        union { unsigned w[2]; u16x4 v; } pd;
        pd.w[0] = pk2(o[0] * rv, o[1] * rv);
        pd.w[1] = pk2(o[2] * rv, o[3] * rv);
        *reinterpret_cast<u16x4*>((char*)out_s + XS(i, head * 64 + nt * 32 + q * 8)) = pd.v;
      }
    }
  }
  __syncthreads();   // out_s complete (proj consumes all heads' columns)

  // ---- fused proj: D[pix][dim] = attnout(49x256) x Wproj^T slice (32 cols/head) ----
  {
    f32x4 pacc[2][4];   // [wsel][p2]
    #pragma unroll
    for (int w = 0; w < 2; ++w)
      #pragma unroll
      for (int p2 = 0; p2 < 4; ++p2)
        pacc[w][p2] = (f32x4){0.f, 0.f, 0.f, 0.f};
    #pragma unroll
    for (int ks = 0; ks < 8; ++ks) {
      const unsigned short* wb = wptab + (size_t)((((head * 8 + ks) * 2) * 64 + lane) * 8);
      bf16x8 wp0 = *reinterpret_cast<const bf16x8*>(wb);
      bf16x8 wp1 = *reinterpret_cast<const bf16x8*>(wb + 512);
      int bc = ks * 64 + q * 16;
      bf16x8 of0 = *reinterpret_cast<const bf16x8*>((const char*)out_s + XS(fr, bc));
      bf16x8 of1 = *reinterpret_cast<const bf16x8*>((const char*)out_s + XS(16 + fr, bc));
      bf16x8 of2 = *reinterpret_cast<const bf16x8*>((const char*)out_s + XS(32 + fr, bc));
      bf16x8 of3 = *reinterpret_cast<const bf16x8*>((const char*)out_s + XS(48 + fr, bc));
      pacc[0][0] = __builtin_amdgcn_mfma_f32_16x16x32_bf16(of0, wp0, pacc[0][0], 0, 0, 0);
      pacc[0][1] = __builtin_amdgcn_mfma_f32_16x16x32_bf16(of1, wp0, pacc[0][1], 0, 0, 0);
      pacc[0][2] = __builtin_amdgcn_mfma_f32_16x16x32_bf16(of2, wp0, pacc[0][2], 0, 0, 0);
      pacc[0][3] = __builtin_amdgcn_mfma_f32_16x16x32_bf16(of3, wp0, pacc[0][3], 0, 0, 0);
      pacc[1][0] = __builtin_amdgcn_mfma_f32_16x16x32_bf16(of0, wp1, pacc[1][0], 0, 0, 0);
      pacc[1][1] = __builtin_amdgcn_mfma_f32_16x16x32_bf16(of1, wp1, pacc[1][1], 0, 0, 0);
      pacc[1][2] = __builtin_amdgcn_mfma_f32_16x16x32_bf16(of2, wp1, pacc[1][2], 0, 0, 0);
      pacc[1][3] = __builtin_amdgcn_mfma_f32_16x16x32_bf16(of3, wp1, pacc[1][3], 0, 0, 0);
    }
    // bias + store: lane holds dim = head*32 + w*16 + fr, pix = p2*16 + q*4 + r
    float bb0 = bproj[head * 32 + fr];
    float bb1 = bproj[head * 32 + 16 + fr];
    #pragma unroll
    for (int p2 = 0; p2 < 4; ++p2) {
      #pragma unroll
      for (int r = 0; r < 4; ++r) {
        int pix = p2 * 16 + q * 4 + r;
        if (pix < 49) {
          float* op = out + (size_t)pix_s[pix] * CDIM + head * 32 + fr;
          op[0]  = pacc[0][p2][r] + bb0;
          op[16] = pacc[1][p2][r] + bb1;
        }
      }
    }
  }
  #undef PACK_MAT
  #undef BUILD_FRAG
  #undef XF_READS
  #undef XS
}

// ---------------- launch ----------------
extern "C" void kernel_launch(void* const* d_in, const int* in_sizes, int n_in,
                              void* d_out, int out_size, void* d_ws, size_t ws_size,
                              hipStream_t stream) {
  const float* x      = (const float*)d_in[0];
  const float* qkv_w  = (const float*)d_in[1];
  const float* qkv_b  = (const float*)d_in[2];
  const float* proj_w = (const float*)d_in[3];
  const float* proj_b = (const float*)d_in[4];
  const float* table  = (const float*)d_in[5];

  char* ws = (char*)d_ws;
  float*          btab  = (float*)ws;                        // 524,288 B
  unsigned short* wtab  = (unsigned short*)(ws + 524288);    // 393,216 B
  unsigned short* wptab = (unsigned short*)(ws + 917504);    // 131,072 B

  prep_kernel<<<640, 256, 0, stream>>>(table, btab, qkv_w, wtab, proj_w, wptab);

  fused_attn<<<2048, 512, 0, stream>>>(x, wtab, qkv_b, btab, wptab, proj_b,
                                       (float*)d_out);
}

// Round 23
// 132.240 us; speedup vs baseline: 2.0030x; 1.0503x over previous
//
#include <hip/hip_runtime.h>
#include <hip/hip_bf16.h>
#include <stdint.h>

typedef __attribute__((ext_vector_type(4))) float f32x4;
typedef __attribute__((ext_vector_type(8))) short bf16x8;
typedef __attribute__((ext_vector_type(8))) unsigned short u16x8;
typedef __attribute__((ext_vector_type(4))) unsigned short u16x4;

#define NPIX 100352      // 32*56*56
#define CDIM 256
#define QKVN 768
#define HWDIM 56

__device__ __forceinline__ unsigned short f2bf(float f) {
  union { float f; unsigned int u; } cv; cv.f = f;
  unsigned int u = cv.u;
  unsigned int r = (u + 0x7FFFu + ((u >> 16) & 1u)) >> 16;
  return (unsigned short)r;
}
__device__ __forceinline__ float bf2f(unsigned short h) {
  union { unsigned int u; float f; } cv; cv.u = ((unsigned int)h) << 16;
  return cv.f;
}
// packed pair convert via official intrinsic (compiler emits v_cvt_pk_bf16_f32)
__device__ __forceinline__ unsigned pk2(float lo, float hi) {
  float2 a; a.x = lo; a.y = hi;
  __hip_bfloat162 h = __float22bfloat162_rn(a);
  union { __hip_bfloat162 h; unsigned u; } cv; cv.h = h;
  return cv.u;
}

// ---------------- merged prep: bias table (f32*log2e) + Wqkv + Wproj fragment tables ----------------
// blocks 0..511: bias_pre | 512..607: wqkv_pre | 608..639: wproj_pre
__global__ __launch_bounds__(256) void prep_kernel(
    const float* __restrict__ table, float* __restrict__ bt,
    const float* __restrict__ wq, unsigned short* __restrict__ wtab,
    const float* __restrict__ wp, unsigned short* __restrict__ wptab)
{
  const int bid = blockIdx.x;
  if (bid < 512) {
    int e = bid * 256 + threadIdx.x;             // 131072 total
    int r  = e & 3;
    int fr = (e >> 2) & 15;
    int q  = (e >> 6) & 3;
    int c2 = (e >> 8) & 3;
    int jf = (e >> 10) & 3;
    int h  = (e >> 12) & 7;
    int cls = (e >> 15) & 3;
    int j = jf * 16 + q * 4 + r;
    int i = c2 * 16 + fr;
    float v;
    if (j > 48 || i > 48) {
      v = -1e30f;
    } else {
      int bh = cls >> 1, bw = cls & 1;
      int iwi = i / 7, iwj = i % 7;
      int jwi = j / 7, jwj = j % 7;
      int ireg = (bh ? ((iwi < 4) ? 1 : 2) : 0) * 3 + (bw ? ((iwj < 4) ? 1 : 2) : 0);
      int jreg = (bh ? ((jwi < 4) ? 1 : 2) : 0) * 3 + (bw ? ((jwj < 4) ? 1 : 2) : 0);
      float m = (ireg == jreg) ? 0.f : -100.f;
      v = (table[((iwi - jwi + 6) * 13 + (iwj - jwj + 6)) * 8 + h] + m) * 1.44269504088896340f;
    }
    bt[e] = v;
  } else if (bid < 608) {
    int e8 = (bid - 512) * 256 + threadIdx.x;    // 24576 total
    int l = e8 & 63;
    int t1 = e8 >> 6;
    int wsel = t1 & 1;
    int ks = (t1 >> 1) & 7;
    int h = (t1 >> 4) & 7;
    int m = t1 >> 7;          // 0..2
    int row = m * 256 + h * 32 + wsel * 16 + (l & 15);
    int col = ks * 32 + (l >> 4) * 8;
    const float4* src = reinterpret_cast<const float4*>(wq + (size_t)row * 256 + col);
    float4 a = src[0], b = src[1];
    u16x8 r;
    r[0] = f2bf(a.x); r[1] = f2bf(a.y); r[2] = f2bf(a.z); r[3] = f2bf(a.w);
    r[4] = f2bf(b.x); r[5] = f2bf(b.y); r[6] = f2bf(b.z); r[7] = f2bf(b.w);
    *reinterpret_cast<u16x8*>(wtab + (size_t)e8 * 8) = r;
  } else {
    int e8 = (bid - 608) * 256 + threadIdx.x;    // 8192 total
    int l = e8 & 63;
    int t1 = e8 >> 6;
    int wsel = t1 & 1;
    int ks = (t1 >> 1) & 7;
    int h = (t1 >> 4) & 7;
    int row = h * 32 + wsel * 16 + (l & 15);
    int col = ks * 32 + (l >> 4) * 8;
    const float4* src = reinterpret_cast<const float4*>(wp + (size_t)row * 256 + col);
    float4 a = src[0], b = src[1];
    u16x8 r;
    r[0] = f2bf(a.x); r[1] = f2bf(a.y); r[2] = f2bf(a.z); r[3] = f2bf(a.w);
    r[4] = f2bf(b.x); r[5] = f2bf(b.y); r[6] = f2bf(b.z); r[7] = f2bf(b.w);
    *reinterpret_cast<u16x8*>(wptab + (size_t)e8 * 8) = r;
  }
}

// ---------------- fully fused: QKV GEMM + shifted-window attention + proj GEMM ----------------
// block = window (512 threads, 8 waves = 8 heads); 2 blocks/CU (LDS-limited)
__global__ __launch_bounds__(512, 2) void fused_attn(
    const float* __restrict__ x,              // [NPIX][256] fp32, pixel order
    const unsigned short* __restrict__ wtab,  // fragment-ordered Wqkv bf16
    const float* __restrict__ bqkv,           // [768]
    const float* __restrict__ btab,           // [4][8][4096] f32 (bias+mask)*log2e
    const unsigned short* __restrict__ wptab, // fragment-ordered Wproj bf16
    const float* __restrict__ bproj,          // [256]
    float* __restrict__ out)                  // [NPIX][256] fp32, pixel order
{
  const int win = blockIdx.x;
  const int b = win >> 6;
  const int gi = (win >> 3) & 7;
  const int gj = win & 7;
  const int t = threadIdx.x;
  const int head = t >> 6;
  const int lane = t & 63;
  const int fr = lane & 15;
  const int q = lane >> 4;

  __shared__ unsigned short x_s[64 * 256];    // x window bf16, rows 49-63 ZERO; reused as out_s
  __shared__ unsigned short Vt[8][32 * 70];   // per head Vt[d][j], stride 70
  __shared__ int pix_s[64];

  // pix map for proj (covered by the staging barrier below)
  if (t < 64) {
    int idx = (t < 49) ? t : 48;
    int wi = idx / 7, wj = idx - (idx / 7) * 7;
    int ph = gi * 7 + wi + 3; if (ph >= HWDIM) ph -= HWDIM;
    int pw = gj * 7 + wj + 3; if (pw >= HWDIM) pw -= HWDIM;
    pix_s[t] = (b * HWDIM + ph) * HWDIM + pw;
  }

  // byte offset into x_s/out_s for (row, bytecol): XOR swizzle -> ~2-way banks
  #define XS(row, bc) ((unsigned)((row) * 512 + (((bc)) ^ (((row) & 7) << 4))))

  // ---- stage x window -> LDS bf16 (rows 49-63 zeroed; 4 uniform iterations) ----
  #pragma unroll
  for (int k = 0; k < 4; ++k) {
    int u = t + 512 * k;
    int pix = u >> 5, seg = u & 31;
    union { unsigned w[4]; u16x8 v; } r;
    if (pix < 49) {
      int wi = pix / 7, wj = pix - (pix / 7) * 7;
      int ph = gi * 7 + wi + 3; if (ph >= HWDIM) ph -= HWDIM;
      int pw = gj * 7 + wj + 3; if (pw >= HWDIM) pw -= HWDIM;
      int pabs = (b * HWDIM + ph) * HWDIM + pw;
      const f32x4* src = reinterpret_cast<const f32x4*>(x + (size_t)pabs * CDIM + seg * 8);
      f32x4 a = __builtin_nontemporal_load(src);
      f32x4 c = __builtin_nontemporal_load(src + 1);
      r.w[0] = pk2(a[0], a[1]); r.w[1] = pk2(a[2], a[3]);
      r.w[2] = pk2(c[0], c[1]); r.w[3] = pk2(c[2], c[3]);
    } else {
      r.w[0] = 0u; r.w[1] = 0u; r.w[2] = 0u; r.w[3] = 0u;
    }
    *reinterpret_cast<u16x8*>((char*)x_s + XS(pix, seg * 16)) = r.v;
  }
  __syncthreads();   // covers x_s AND pix_s

  const int cls = (((gi == 7) ? 1 : 0) << 1) | ((gj == 7) ? 1 : 0);
  const float* bth = btab + (((cls << 3) | head) << 12);
  unsigned short* VtW = Vt[head];
  const int srcA = ((q & 1) << 5) + fr;
  const int srcB = srcA + 16;
  const bool hi = (q >= 2);

  #define PACK_MAT(accm, pkm)                                                          \
  { _Pragma("unroll") for (int d = 0; d < 2; ++d)                                      \
      _Pragma("unroll") for (int p2 = 0; p2 < 4; ++p2) {                               \
        pkm[d][p2][0] = pk2(accm[d][p2][0], accm[d][p2][1]);                           \
        pkm[d][p2][1] = pk2(accm[d][p2][2], accm[d][p2][3]);                           \
      } }

  #define BUILD_FRAG(pkm, p2, dst)                                                     \
  { unsigned a0 = (unsigned)__shfl((int)pkm[0][p2][0], srcA);                          \
    unsigned a1 = (unsigned)__shfl((int)pkm[0][p2][1], srcA);                          \
    unsigned a2 = (unsigned)__shfl((int)pkm[0][p2][0], srcB);                          \
    unsigned a3 = (unsigned)__shfl((int)pkm[0][p2][1], srcB);                          \
    unsigned b0 = (unsigned)__shfl((int)pkm[1][p2][0], srcA);                          \
    unsigned b1 = (unsigned)__shfl((int)pkm[1][p2][1], srcA);                          \
    unsigned b2 = (unsigned)__shfl((int)pkm[1][p2][0], srcB);                          \
    unsigned b3 = (unsigned)__shfl((int)pkm[1][p2][1], srcB);                          \
    union { unsigned u[4]; bf16x8 v; } uf;                                             \
    uf.u[0] = hi ? b0 : a0; uf.u[1] = hi ? b1 : a1;                                    \
    uf.u[2] = hi ? b2 : a2; uf.u[3] = hi ? b3 : a3;                                    \
    dst = uf.v; }

  #define XF_READS                                                                     \
    int bc = ks * 64 + q * 16;                                                         \
    bf16x8 xf0 = *reinterpret_cast<const bf16x8*>((const char*)x_s + XS(fr, bc));      \
    bf16x8 xf1 = *reinterpret_cast<const bf16x8*>((const char*)x_s + XS(16 + fr, bc)); \
    bf16x8 xf2 = *reinterpret_cast<const bf16x8*>((const char*)x_s + XS(32 + fr, bc)); \
    bf16x8 xf3 = *reinterpret_cast<const bf16x8*>((const char*)x_s + XS(48 + fr, bc));

  unsigned pkk[2][4][2], pkq[2][4][2];

  // ---- pass V: compute V, scatter to Vt (acc dies into LDS) ----
  {
    f32x4 acc[2][4];
    #pragma unroll
    for (int d = 0; d < 2; ++d)
      #pragma unroll
      for (int p2 = 0; p2 < 4; ++p2)
        acc[d][p2] = (f32x4){0.f, 0.f, 0.f, 0.f};
    #pragma unroll
    for (int ks = 0; ks < 8; ++ks) {
      const unsigned short* wb = wtab + (size_t)((((2 * 8 + head) * 8 + ks) * 128 + lane) * 8);
      bf16x8 wf0 = *reinterpret_cast<const bf16x8*>(wb);
      bf16x8 wf1 = *reinterpret_cast<const bf16x8*>(wb + 512);
      XF_READS
      acc[0][0] = __builtin_amdgcn_mfma_f32_16x16x32_bf16(wf0, xf0, acc[0][0], 0, 0, 0);
      acc[0][1] = __builtin_amdgcn_mfma_f32_16x16x32_bf16(wf0, xf1, acc[0][1], 0, 0, 0);
      acc[0][2] = __builtin_amdgcn_mfma_f32_16x16x32_bf16(wf0, xf2, acc[0][2], 0, 0, 0);
      acc[0][3] = __builtin_amdgcn_mfma_f32_16x16x32_bf16(wf0, xf3, acc[0][3], 0, 0, 0);
      acc[1][0] = __builtin_amdgcn_mfma_f32_16x16x32_bf16(wf1, xf0, acc[1][0], 0, 0, 0);
      acc[1][1] = __builtin_amdgcn_mfma_f32_16x16x32_bf16(wf1, xf1, acc[1][1], 0, 0, 0);
      acc[1][2] = __builtin_amdgcn_mfma_f32_16x16x32_bf16(wf1, xf2, acc[1][2], 0, 0, 0);
      acc[1][3] = __builtin_amdgcn_mfma_f32_16x16x32_bf16(wf1, xf3, acc[1][3], 0, 0, 0);
    }
    #pragma unroll
    for (int d = 0; d < 2; ++d) {
      f32x4 bv = *reinterpret_cast<const f32x4*>(bqkv + 512 + head * 32 + d * 16 + q * 4);
      #pragma unroll
      for (int p2 = 0; p2 < 4; ++p2) {
        f32x4 v = acc[d][p2] + bv;
        #pragma unroll
        for (int r = 0; r < 4; ++r)
          VtW[(d * 16 + q * 4 + r) * 70 + p2 * 16 + fr] = f2bf(v[r]);
      }
    }
  }

  // ---- pass K+Q fused: one xf read feeds both weight sets ----
  {
    f32x4 acck[2][4], accq[2][4];
    #pragma unroll
    for (int d = 0; d < 2; ++d)
      #pragma unroll
      for (int p2 = 0; p2 < 4; ++p2) {
        acck[d][p2] = (f32x4){0.f, 0.f, 0.f, 0.f};
        accq[d][p2] = (f32x4){0.f, 0.f, 0.f, 0.f};
      }
    #pragma unroll
    for (int ks = 0; ks < 8; ++ks) {
      const unsigned short* wbK = wtab + (size_t)((((1 * 8 + head) * 8 + ks) * 128 + lane) * 8);
      const unsigned short* wbQ = wtab + (size_t)((((0 * 8 + head) * 8 + ks) * 128 + lane) * 8);
      bf16x8 wk0 = *reinterpret_cast<const bf16x8*>(wbK);
      bf16x8 wk1 = *reinterpret_cast<const bf16x8*>(wbK + 512);
      bf16x8 wq0 = *reinterpret_cast<const bf16x8*>(wbQ);
      bf16x8 wq1 = *reinterpret_cast<const bf16x8*>(wbQ + 512);
      XF_READS
      acck[0][0] = __builtin_amdgcn_mfma_f32_16x16x32_bf16(wk0, xf0, acck[0][0], 0, 0, 0);
      acck[0][1] = __builtin_amdgcn_mfma_f32_16x16x32_bf16(wk0, xf1, acck[0][1], 0, 0, 0);
      acck[0][2] = __builtin_amdgcn_mfma_f32_16x16x32_bf16(wk0, xf2, acck[0][2], 0, 0, 0);
      acck[0][3] = __builtin_amdgcn_mfma_f32_16x16x32_bf16(wk0, xf3, acck[0][3], 0, 0, 0);
      acck[1][0] = __builtin_amdgcn_mfma_f32_16x16x32_bf16(wk1, xf0, acck[1][0], 0, 0, 0);
      acck[1][1] = __builtin_amdgcn_mfma_f32_16x16x32_bf16(wk1, xf1, acck[1][1], 0, 0, 0);
      acck[1][2] = __builtin_amdgcn_mfma_f32_16x16x32_bf16(wk1, xf2, acck[1][2], 0, 0, 0);
      acck[1][3] = __builtin_amdgcn_mfma_f32_16x16x32_bf16(wk1, xf3, acck[1][3], 0, 0, 0);
      accq[0][0] = __builtin_amdgcn_mfma_f32_16x16x32_bf16(wq0, xf0, accq[0][0], 0, 0, 0);
      accq[0][1] = __builtin_amdgcn_mfma_f32_16x16x32_bf16(wq0, xf1, accq[0][1], 0, 0, 0);
      accq[0][2] = __builtin_amdgcn_mfma_f32_16x16x32_bf16(wq0, xf2, accq[0][2], 0, 0, 0);
      accq[0][3] = __builtin_amdgcn_mfma_f32_16x16x32_bf16(wq0, xf3, accq[0][3], 0, 0, 0);
      accq[1][0] = __builtin_amdgcn_mfma_f32_16x16x32_bf16(wq1, xf0, accq[1][0], 0, 0, 0);
      accq[1][1] = __builtin_amdgcn_mfma_f32_16x16x32_bf16(wq1, xf1, accq[1][1], 0, 0, 0);
      accq[1][2] = __builtin_amdgcn_mfma_f32_16x16x32_bf16(wq1, xf2, accq[1][2], 0, 0, 0);
      accq[1][3] = __builtin_amdgcn_mfma_f32_16x16x32_bf16(wq1, xf3, accq[1][3], 0, 0, 0);
    }
    #pragma unroll
    for (int d = 0; d < 2; ++d) {
      f32x4 bvk = *reinterpret_cast<const f32x4*>(bqkv + 256 + head * 32 + d * 16 + q * 4);
      f32x4 bvq = *reinterpret_cast<const f32x4*>(bqkv +       head * 32 + d * 16 + q * 4);
      #pragma unroll
      for (int p2 = 0; p2 < 4; ++p2) {
        acck[d][p2] += bvk;
        accq[d][p2] += bvq;
      }
    }
    PACK_MAT(acck, pkk);
    PACK_MAT(accq, pkq);
  }

  bf16x8 qf[4];
  BUILD_FRAG(pkq, 0, qf[0]); BUILD_FRAG(pkq, 1, qf[1]);
  BUILD_FRAG(pkq, 2, qf[2]); BUILD_FRAG(pkq, 3, qf[3]);

  // ---- S^T + softmax (base-2: scale and bias pre-multiplied by log2e) ----
  const float scale = 0.17677669529663687f * 1.44269504088896340f;
  f32x4 aw[2][4];
  #pragma unroll
  for (int c2 = 0; c2 < 4; ++c2)
    aw[0][c2] = *reinterpret_cast<const f32x4*>(bth + (c2 << 8) + (q << 6) + (fr << 2));
  float colsum[4] = {0.f, 0.f, 0.f, 0.f};
  unsigned pk[4][4][2];
  #pragma unroll
  for (int jf = 0; jf < 4; ++jf) {
    bf16x8 kfj;
    BUILD_FRAG(pkk, jf, kfj);
    f32x4 sacc[4];
    #pragma unroll
    for (int c2 = 0; c2 < 4; ++c2) {
      f32x4 z = {0.f, 0.f, 0.f, 0.f};
      sacc[c2] = __builtin_amdgcn_mfma_f32_16x16x32_bf16(kfj, qf[c2], z, 0, 0, 0);
    }
    if (jf < 3) {
      #pragma unroll
      for (int c2 = 0; c2 < 4; ++c2)
        aw[(jf + 1) & 1][c2] = *reinterpret_cast<const f32x4*>(
            bth + (((jf + 1) * 4 + c2) << 8) + (q << 6) + (fr << 2));
    }
    #pragma unroll
    for (int c2 = 0; c2 < 4; ++c2) {
      float ev[4];
      #pragma unroll
      for (int r = 0; r < 4; ++r) {
        float val = fmaf(sacc[c2][r], scale, aw[jf & 1][c2][r]);
        ev[r] = __builtin_amdgcn_exp2f(val);
        colsum[c2] += ev[r];
      }
      pk[jf][c2][0] = pk2(ev[0], ev[1]);
      pk[jf][c2][1] = pk2(ev[2], ev[3]);
    }
  }
  float rinv[4];
  #pragma unroll
  for (int c2 = 0; c2 < 4; ++c2) {
    float s = colsum[c2];
    s += __shfl_xor(s, 16);
    s += __shfl_xor(s, 32);
    rinv[c2] = 1.0f / s;
  }

  // ---- PV: attnT[d][i] = sum_j Vt[d][j] * P^T[j][i] ----
  f32x4 outT[2][4] = {};
  #pragma unroll
  for (int kb = 0; kb < 2; ++kb) {
    bf16x8 vf0 = *reinterpret_cast<const bf16x8*>(&VtW[(fr)      * 70 + kb * 32 + q * 8]);
    bf16x8 vf1 = *reinterpret_cast<const bf16x8*>(&VtW[(16 + fr) * 70 + kb * 32 + q * 8]);
    #pragma unroll
    for (int c2 = 0; c2 < 4; ++c2) {
      bf16x8 pf;
      {
        unsigned a0 = (unsigned)__shfl((int)pk[2 * kb][c2][0], srcA);
        unsigned a1 = (unsigned)__shfl((int)pk[2 * kb][c2][1], srcA);
        unsigned a2 = (unsigned)__shfl((int)pk[2 * kb][c2][0], srcB);
        unsigned a3 = (unsigned)__shfl((int)pk[2 * kb][c2][1], srcB);
        unsigned b0 = (unsigned)__shfl((int)pk[2 * kb + 1][c2][0], srcA);
        unsigned b1 = (unsigned)__shfl((int)pk[2 * kb + 1][c2][1], srcA);
        unsigned b2 = (unsigned)__shfl((int)pk[2 * kb + 1][c2][0], srcB);
        unsigned b3 = (unsigned)__shfl((int)pk[2 * kb + 1][c2][1], srcB);
        union { unsigned u[4]; bf16x8 v; } pfv;
        pfv.u[0] = hi ? b0 : a0;
        pfv.u[1] = hi ? b1 : a1;
        pfv.u[2] = hi ? b2 : a2;
        pfv.u[3] = hi ? b3 : a3;
        pf = pfv.v;
      }
      outT[0][c2] = __builtin_amdgcn_mfma_f32_16x16x32_bf16(vf0, pf, outT[0][c2], 0, 0, 0);
      outT[1][c2] = __builtin_amdgcn_mfma_f32_16x16x32_bf16(vf1, pf, outT[1][c2], 0, 0, 0);
    }
  }

  // ---- stage attnout in LDS (reuse x_s region rows 0-48; rows 49-63 stay zero) ----
  unsigned short* out_s = x_s;
  __syncthreads();   // all waves done reading x_s / own Vt
  #pragma unroll
  for (int c2 = 0; c2 < 4; ++c2) {
    int i = c2 * 16 + fr;
    if (i < 49) {
      float rv = rinv[c2];
      #pragma unroll
      for (int nt = 0; nt < 2; ++nt) {
        f32x4 o = outT[nt][c2];
        union { unsigned w[2]; u16x4 v; } pd;
        pd.w[0] = pk2(o[0] * rv, o[1] * rv);
        pd.w[1] = pk2(o[2] * rv, o[3] * rv);
        *reinterpret_cast<u16x4*>((char*)out_s + XS(i, head * 64 + nt * 32 + q * 8)) = pd.v;
      }
    }
  }
  __syncthreads();   // out_s complete (proj consumes all heads' columns)

  // ---- fused proj: D[pix][dim] = attnout(49x256) x Wproj^T slice (32 cols/head) ----
  {
    f32x4 pacc[2][4];   // [wsel][p2]
    #pragma unroll
    for (int w = 0; w < 2; ++w)
      #pragma unroll
      for (int p2 = 0; p2 < 4; ++p2)
        pacc[w][p2] = (f32x4){0.f, 0.f, 0.f, 0.f};
    #pragma unroll
    for (int ks = 0; ks < 8; ++ks) {
      const unsigned short* wb = wptab + (size_t)((((head * 8 + ks) * 2) * 64 + lane) * 8);
      bf16x8 wp0 = *reinterpret_cast<const bf16x8*>(wb);
      bf16x8 wp1 = *reinterpret_cast<const bf16x8*>(wb + 512);
      int bc = ks * 64 + q * 16;
      bf16x8 of0 = *reinterpret_cast<const bf16x8*>((const char*)out_s + XS(fr, bc));
      bf16x8 of1 = *reinterpret_cast<const bf16x8*>((const char*)out_s + XS(16 + fr, bc));
      bf16x8 of2 = *reinterpret_cast<const bf16x8*>((const char*)out_s + XS(32 + fr, bc));
      bf16x8 of3 = *reinterpret_cast<const bf16x8*>((const char*)out_s + XS(48 + fr, bc));
      pacc[0][0] = __builtin_amdgcn_mfma_f32_16x16x32_bf16(of0, wp0, pacc[0][0], 0, 0, 0);
      pacc[0][1] = __builtin_amdgcn_mfma_f32_16x16x32_bf16(of1, wp0, pacc[0][1], 0, 0, 0);
      pacc[0][2] = __builtin_amdgcn_mfma_f32_16x16x32_bf16(of2, wp0, pacc[0][2], 0, 0, 0);
      pacc[0][3] = __builtin_amdgcn_mfma_f32_16x16x32_bf16(of3, wp0, pacc[0][3], 0, 0, 0);
      pacc[1][0] = __builtin_amdgcn_mfma_f32_16x16x32_bf16(of0, wp1, pacc[1][0], 0, 0, 0);
      pacc[1][1] = __builtin_amdgcn_mfma_f32_16x16x32_bf16(of1, wp1, pacc[1][1], 0, 0, 0);
      pacc[1][2] = __builtin_amdgcn_mfma_f32_16x16x32_bf16(of2, wp1, pacc[1][2], 0, 0, 0);
      pacc[1][3] = __builtin_amdgcn_mfma_f32_16x16x32_bf16(of3, wp1, pacc[1][3], 0, 0, 0);
    }
    // bias + store: lane holds dim = head*32 + w*16 + fr, pix = p2*16 + q*4 + r
    float bb0 = bproj[head * 32 + fr];
    float bb1 = bproj[head * 32 + 16 + fr];
    #pragma unroll
    for (int p2 = 0; p2 < 4; ++p2) {
      #pragma unroll
      for (int r = 0; r < 4; ++r) {
        int pix = p2 * 16 + q * 4 + r;
        if (pix < 49) {
          float* op = out + (size_t)pix_s[pix] * CDIM + head * 32 + fr;
          __builtin_nontemporal_store(pacc[0][p2][r] + bb0, op);
          __builtin_nontemporal_store(pacc[1][p2][r] + bb1, op + 16);
        }
      }
    }
  }
  #undef PACK_MAT
  #undef BUILD_FRAG
  #undef XF_READS
  #undef XS
}

// ---------------- launch ----------------
extern "C" void kernel_launch(void* const* d_in, const int* in_sizes, int n_in,
                              void* d_out, int out_size, void* d_ws, size_t ws_size,
                              hipStream_t stream) {
  const float* x      = (const float*)d_in[0];
  const float* qkv_w  = (const float*)d_in[1];
  const float* qkv_b  = (const float*)d_in[2];
  const float* proj_w = (const float*)d_in[3];
  const float* proj_b = (const float*)d_in[4];
  const float* table  = (const float*)d_in[5];

  char* ws = (char*)d_ws;
  float*          btab  = (float*)ws;                        // 524,288 B
  unsigned short* wtab  = (unsigned short*)(ws + 524288);    // 393,216 B
  unsigned short* wptab = (unsigned short*)(ws + 917504);    // 131,072 B

  prep_kernel<<<640, 256, 0, stream>>>(table, btab, qkv_w, wtab, proj_w, wptab);

  fused_attn<<<2048, 512, 0, stream>>>(x, wtab, qkv_b, btab, wptab, proj_b,
                                       (float*)d_out);
}

// Round 24
// 125.858 us; speedup vs baseline: 2.1046x; 1.0507x over previous
//
#include <hip/hip_runtime.h>
#include <hip/hip_bf16.h>
#include <stdint.h>

typedef __attribute__((ext_vector_type(4))) float f32x4;
typedef __attribute__((ext_vector_type(8))) short bf16x8;
typedef __attribute__((ext_vector_type(8))) unsigned short u16x8;
typedef __attribute__((ext_vector_type(4))) unsigned short u16x4;

#define NPIX 100352      // 32*56*56
#define CDIM 256
#define QKVN 768
#define HWDIM 56
#define VSTR 72          // Vt row stride (elements); 144 B = 16B-aligned rows

__device__ __forceinline__ unsigned short f2bf(float f) {
  union { float f; unsigned int u; } cv; cv.f = f;
  unsigned int u = cv.u;
  unsigned int r = (u + 0x7FFFu + ((u >> 16) & 1u)) >> 16;
  return (unsigned short)r;
}
__device__ __forceinline__ float bf2f(unsigned short h) {
  union { unsigned int u; float f; } cv; cv.u = ((unsigned int)h) << 16;
  return cv.f;
}
// packed pair convert via official intrinsic (compiler emits v_cvt_pk_bf16_f32)
__device__ __forceinline__ unsigned pk2(float lo, float hi) {
  float2 a; a.x = lo; a.y = hi;
  __hip_bfloat162 h = __float22bfloat162_rn(a);
  union { __hip_bfloat162 h; unsigned u; } cv; cv.h = h;
  return cv.u;
}

// ---------------- merged prep: bias table (f32*log2e) + Wqkv + Wproj fragment tables ----------------
// blocks 0..511: bias_pre | 512..607: wqkv_pre | 608..639: wproj_pre
__global__ __launch_bounds__(256) void prep_kernel(
    const float* __restrict__ table, float* __restrict__ bt,
    const float* __restrict__ wq, unsigned short* __restrict__ wtab,
    const float* __restrict__ wp, unsigned short* __restrict__ wptab)
{
  const int bid = blockIdx.x;
  if (bid < 512) {
    int e = bid * 256 + threadIdx.x;             // 131072 total
    int r  = e & 3;
    int fr = (e >> 2) & 15;
    int q  = (e >> 6) & 3;
    int c2 = (e >> 8) & 3;
    int jf = (e >> 10) & 3;
    int h  = (e >> 12) & 7;
    int cls = (e >> 15) & 3;
    int j = jf * 16 + q * 4 + r;
    int i = c2 * 16 + fr;
    float v;
    if (j > 48 || i > 48) {
      v = -1e30f;
    } else {
      int bh = cls >> 1, bw = cls & 1;
      int iwi = i / 7, iwj = i % 7;
      int jwi = j / 7, jwj = j % 7;
      int ireg = (bh ? ((iwi < 4) ? 1 : 2) : 0) * 3 + (bw ? ((iwj < 4) ? 1 : 2) : 0);
      int jreg = (bh ? ((jwi < 4) ? 1 : 2) : 0) * 3 + (bw ? ((jwj < 4) ? 1 : 2) : 0);
      float m = (ireg == jreg) ? 0.f : -100.f;
      v = (table[((iwi - jwi + 6) * 13 + (iwj - jwj + 6)) * 8 + h] + m) * 1.44269504088896340f;
    }
    bt[e] = v;
  } else if (bid < 608) {
    int e8 = (bid - 512) * 256 + threadIdx.x;    // 24576 total
    int l = e8 & 63;
    int t1 = e8 >> 6;
    int wsel = t1 & 1;
    int ks = (t1 >> 1) & 7;
    int h = (t1 >> 4) & 7;
    int m = t1 >> 7;          // 0..2
    int row = m * 256 + h * 32 + wsel * 16 + (l & 15);
    int col = ks * 32 + (l >> 4) * 8;
    const float4* src = reinterpret_cast<const float4*>(wq + (size_t)row * 256 + col);
    float4 a = src[0], b = src[1];
    u16x8 r;
    r[0] = f2bf(a.x); r[1] = f2bf(a.y); r[2] = f2bf(a.z); r[3] = f2bf(a.w);
    r[4] = f2bf(b.x); r[5] = f2bf(b.y); r[6] = f2bf(b.z); r[7] = f2bf(b.w);
    *reinterpret_cast<u16x8*>(wtab + (size_t)e8 * 8) = r;
  } else {
    int e8 = (bid - 608) * 256 + threadIdx.x;    // 8192 total
    int l = e8 & 63;
    int t1 = e8 >> 6;
    int wsel = t1 & 1;
    int ks = (t1 >> 1) & 7;
    int h = (t1 >> 4) & 7;
    int row = h * 32 + wsel * 16 + (l & 15);
    int col = ks * 32 + (l >> 4) * 8;
    const float4* src = reinterpret_cast<const float4*>(wp + (size_t)row * 256 + col);
    float4 a = src[0], b = src[1];
    u16x8 r;
    r[0] = f2bf(a.x); r[1] = f2bf(a.y); r[2] = f2bf(a.z); r[3] = f2bf(a.w);
    r[4] = f2bf(b.x); r[5] = f2bf(b.y); r[6] = f2bf(b.z); r[7] = f2bf(b.w);
    *reinterpret_cast<u16x8*>(wptab + (size_t)e8 * 8) = r;
  }
}

// ---------------- fully fused: QKV GEMM + shifted-window attention + proj GEMM ----------------
// block = window (512 threads, 8 waves = 8 heads); 2 blocks/CU (LDS-limited)
__global__ __launch_bounds__(512, 2) void fused_attn(
    const float* __restrict__ x,              // [NPIX][256] fp32, pixel order
    const unsigned short* __restrict__ wtab,  // fragment-ordered Wqkv bf16
    const float* __restrict__ bqkv,           // [768]
    const float* __restrict__ btab,           // [4][8][4096] f32 (bias+mask)*log2e
    const unsigned short* __restrict__ wptab, // fragment-ordered Wproj bf16
    const float* __restrict__ bproj,          // [256]
    float* __restrict__ out)                  // [NPIX][256] fp32, pixel order
{
  const int win = blockIdx.x;
  const int b = win >> 6;
  const int gi = (win >> 3) & 7;
  const int gj = win & 7;
  const int t = threadIdx.x;
  const int head = t >> 6;
  const int lane = t & 63;
  const int fr = lane & 15;
  const int q = lane >> 4;

  __shared__ unsigned short x_s[64 * 256];     // x window bf16, rows 49-63 ZERO; reused as out_s
  __shared__ unsigned short Vt[8][32 * VSTR];  // per head Vt[d][j], 16B-aligned rows
  __shared__ int pix_s[64];

  // pix map for proj (covered by the staging barrier below)
  if (t < 64) {
    int idx = (t < 49) ? t : 48;
    int wi = idx / 7, wj = idx - (idx / 7) * 7;
    int ph = gi * 7 + wi + 3; if (ph >= HWDIM) ph -= HWDIM;
    int pw = gj * 7 + wj + 3; if (pw >= HWDIM) pw -= HWDIM;
    pix_s[t] = (b * HWDIM + ph) * HWDIM + pw;
  }

  // byte offset into x_s/out_s for (row, bytecol): XOR swizzle -> ~2-way banks
  #define XS(row, bc) ((unsigned)((row) * 512 + (((bc)) ^ (((row) & 7) << 4))))

  // ---- stage x window -> LDS bf16 (rows 49-63 zeroed; 4 uniform iterations) ----
  #pragma unroll
  for (int k = 0; k < 4; ++k) {
    int u = t + 512 * k;
    int pix = u >> 5, seg = u & 31;
    union { unsigned w[4]; u16x8 v; } r;
    if (pix < 49) {
      int wi = pix / 7, wj = pix - (pix / 7) * 7;
      int ph = gi * 7 + wi + 3; if (ph >= HWDIM) ph -= HWDIM;
      int pw = gj * 7 + wj + 3; if (pw >= HWDIM) pw -= HWDIM;
      int pabs = (b * HWDIM + ph) * HWDIM + pw;
      const f32x4* src = reinterpret_cast<const f32x4*>(x + (size_t)pabs * CDIM + seg * 8);
      f32x4 a = __builtin_nontemporal_load(src);
      f32x4 c = __builtin_nontemporal_load(src + 1);
      r.w[0] = pk2(a[0], a[1]); r.w[1] = pk2(a[2], a[3]);
      r.w[2] = pk2(c[0], c[1]); r.w[3] = pk2(c[2], c[3]);
    } else {
      r.w[0] = 0u; r.w[1] = 0u; r.w[2] = 0u; r.w[3] = 0u;
    }
    *reinterpret_cast<u16x8*>((char*)x_s + XS(pix, seg * 16)) = r.v;
  }
  __syncthreads();   // covers x_s AND pix_s

  const int cls = (((gi == 7) ? 1 : 0) << 1) | ((gj == 7) ? 1 : 0);
  const float* bth = btab + (((cls << 3) | head) << 12);
  unsigned short* VtW = Vt[head];
  const int srcA = ((q & 1) << 5) + fr;
  const int srcB = srcA + 16;
  const bool hi = (q >= 2);

  #define PACK_MAT(accm, pkm)                                                          \
  { _Pragma("unroll") for (int d = 0; d < 2; ++d)                                      \
      _Pragma("unroll") for (int p2 = 0; p2 < 4; ++p2) {                               \
        pkm[d][p2][0] = pk2(accm[d][p2][0], accm[d][p2][1]);                           \
        pkm[d][p2][1] = pk2(accm[d][p2][2], accm[d][p2][3]);                           \
      } }

  #define BUILD_FRAG(pkm, p2, dst)                                                     \
  { unsigned a0 = (unsigned)__shfl((int)pkm[0][p2][0], srcA);                          \
    unsigned a1 = (unsigned)__shfl((int)pkm[0][p2][1], srcA);                          \
    unsigned a2 = (unsigned)__shfl((int)pkm[0][p2][0], srcB);                          \
    unsigned a3 = (unsigned)__shfl((int)pkm[0][p2][1], srcB);                          \
    unsigned b0 = (unsigned)__shfl((int)pkm[1][p2][0], srcA);                          \
    unsigned b1 = (unsigned)__shfl((int)pkm[1][p2][1], srcA);                          \
    unsigned b2 = (unsigned)__shfl((int)pkm[1][p2][0], srcB);                          \
    unsigned b3 = (unsigned)__shfl((int)pkm[1][p2][1], srcB);                          \
    union { unsigned u[4]; bf16x8 v; } uf;                                             \
    uf.u[0] = hi ? b0 : a0; uf.u[1] = hi ? b1 : a1;                                    \
    uf.u[2] = hi ? b2 : a2; uf.u[3] = hi ? b3 : a3;                                    \
    dst = uf.v; }

  #define XF_READS                                                                     \
    int bc = ks * 64 + q * 16;                                                         \
    bf16x8 xf0 = *reinterpret_cast<const bf16x8*>((const char*)x_s + XS(fr, bc));      \
    bf16x8 xf1 = *reinterpret_cast<const bf16x8*>((const char*)x_s + XS(16 + fr, bc)); \
    bf16x8 xf2 = *reinterpret_cast<const bf16x8*>((const char*)x_s + XS(32 + fr, bc)); \
    bf16x8 xf3 = *reinterpret_cast<const bf16x8*>((const char*)x_s + XS(48 + fr, bc));

  unsigned pkk[2][4][2], pkq[2][4][2];

  // ---- pass V: compute V, scatter to Vt (acc dies into LDS) ----
  {
    f32x4 acc[2][4];
    #pragma unroll
    for (int d = 0; d < 2; ++d)
      #pragma unroll
      for (int p2 = 0; p2 < 4; ++p2)
        acc[d][p2] = (f32x4){0.f, 0.f, 0.f, 0.f};
    #pragma unroll
    for (int ks = 0; ks < 8; ++ks) {
      const unsigned short* wb = wtab + (size_t)((((2 * 8 + head) * 8 + ks) * 128 + lane) * 8);
      bf16x8 wf0 = *reinterpret_cast<const bf16x8*>(wb);
      bf16x8 wf1 = *reinterpret_cast<const bf16x8*>(wb + 512);
      XF_READS
      acc[0][0] = __builtin_amdgcn_mfma_f32_16x16x32_bf16(wf0, xf0, acc[0][0], 0, 0, 0);
      acc[0][1] = __builtin_amdgcn_mfma_f32_16x16x32_bf16(wf0, xf1, acc[0][1], 0, 0, 0);
      acc[0][2] = __builtin_amdgcn_mfma_f32_16x16x32_bf16(wf0, xf2, acc[0][2], 0, 0, 0);
      acc[0][3] = __builtin_amdgcn_mfma_f32_16x16x32_bf16(wf0, xf3, acc[0][3], 0, 0, 0);
      acc[1][0] = __builtin_amdgcn_mfma_f32_16x16x32_bf16(wf1, xf0, acc[1][0], 0, 0, 0);
      acc[1][1] = __builtin_amdgcn_mfma_f32_16x16x32_bf16(wf1, xf1, acc[1][1], 0, 0, 0);
      acc[1][2] = __builtin_amdgcn_mfma_f32_16x16x32_bf16(wf1, xf2, acc[1][2], 0, 0, 0);
      acc[1][3] = __builtin_amdgcn_mfma_f32_16x16x32_bf16(wf1, xf3, acc[1][3], 0, 0, 0);
    }
    #pragma unroll
    for (int d = 0; d < 2; ++d) {
      f32x4 bv = *reinterpret_cast<const f32x4*>(bqkv + 512 + head * 32 + d * 16 + q * 4);
      #pragma unroll
      for (int p2 = 0; p2 < 4; ++p2) {
        f32x4 v = acc[d][p2] + bv;
        #pragma unroll
        for (int r = 0; r < 4; ++r)
          VtW[(d * 16 + q * 4 + r) * VSTR + p2 * 16 + fr] = f2bf(v[r]);
      }
    }
  }

  // ---- pass K+Q fused: one xf read feeds both weight sets ----
  {
    f32x4 acck[2][4], accq[2][4];
    #pragma unroll
    for (int d = 0; d < 2; ++d)
      #pragma unroll
      for (int p2 = 0; p2 < 4; ++p2) {
        acck[d][p2] = (f32x4){0.f, 0.f, 0.f, 0.f};
        accq[d][p2] = (f32x4){0.f, 0.f, 0.f, 0.f};
      }
    #pragma unroll
    for (int ks = 0; ks < 8; ++ks) {
      const unsigned short* wbK = wtab + (size_t)((((1 * 8 + head) * 8 + ks) * 128 + lane) * 8);
      const unsigned short* wbQ = wtab + (size_t)((((0 * 8 + head) * 8 + ks) * 128 + lane) * 8);
      bf16x8 wk0 = *reinterpret_cast<const bf16x8*>(wbK);
      bf16x8 wk1 = *reinterpret_cast<const bf16x8*>(wbK + 512);
      bf16x8 wq0 = *reinterpret_cast<const bf16x8*>(wbQ);
      bf16x8 wq1 = *reinterpret_cast<const bf16x8*>(wbQ + 512);
      XF_READS
      acck[0][0] = __builtin_amdgcn_mfma_f32_16x16x32_bf16(wk0, xf0, acck[0][0], 0, 0, 0);
      acck[0][1] = __builtin_amdgcn_mfma_f32_16x16x32_bf16(wk0, xf1, acck[0][1], 0, 0, 0);
      acck[0][2] = __builtin_amdgcn_mfma_f32_16x16x32_bf16(wk0, xf2, acck[0][2], 0, 0, 0);
      acck[0][3] = __builtin_amdgcn_mfma_f32_16x16x32_bf16(wk0, xf3, acck[0][3], 0, 0, 0);
      acck[1][0] = __builtin_amdgcn_mfma_f32_16x16x32_bf16(wk1, xf0, acck[1][0], 0, 0, 0);
      acck[1][1] = __builtin_amdgcn_mfma_f32_16x16x32_bf16(wk1, xf1, acck[1][1], 0, 0, 0);
      acck[1][2] = __builtin_amdgcn_mfma_f32_16x16x32_bf16(wk1, xf2, acck[1][2], 0, 0, 0);
      acck[1][3] = __builtin_amdgcn_mfma_f32_16x16x32_bf16(wk1, xf3, acck[1][3], 0, 0, 0);
      accq[0][0] = __builtin_amdgcn_mfma_f32_16x16x32_bf16(wq0, xf0, accq[0][0], 0, 0, 0);
      accq[0][1] = __builtin_amdgcn_mfma_f32_16x16x32_bf16(wq0, xf1, accq[0][1], 0, 0, 0);
      accq[0][2] = __builtin_amdgcn_mfma_f32_16x16x32_bf16(wq0, xf2, accq[0][2], 0, 0, 0);
      accq[0][3] = __builtin_amdgcn_mfma_f32_16x16x32_bf16(wq0, xf3, accq[0][3], 0, 0, 0);
      accq[1][0] = __builtin_amdgcn_mfma_f32_16x16x32_bf16(wq1, xf0, accq[1][0], 0, 0, 0);
      accq[1][1] = __builtin_amdgcn_mfma_f32_16x16x32_bf16(wq1, xf1, accq[1][1], 0, 0, 0);
      accq[1][2] = __builtin_amdgcn_mfma_f32_16x16x32_bf16(wq1, xf2, accq[1][2], 0, 0, 0);
      accq[1][3] = __builtin_amdgcn_mfma_f32_16x16x32_bf16(wq1, xf3, accq[1][3], 0, 0, 0);
    }
    #pragma unroll
    for (int d = 0; d < 2; ++d) {
      f32x4 bvk = *reinterpret_cast<const f32x4*>(bqkv + 256 + head * 32 + d * 16 + q * 4);
      f32x4 bvq = *reinterpret_cast<const f32x4*>(bqkv +       head * 32 + d * 16 + q * 4);
      #pragma unroll
      for (int p2 = 0; p2 < 4; ++p2) {
        acck[d][p2] += bvk;
        accq[d][p2] += bvq;
      }
    }
    PACK_MAT(acck, pkk);
    PACK_MAT(accq, pkq);
  }

  bf16x8 qf[4];
  BUILD_FRAG(pkq, 0, qf[0]); BUILD_FRAG(pkq, 1, qf[1]);
  BUILD_FRAG(pkq, 2, qf[2]); BUILD_FRAG(pkq, 3, qf[3]);

  // ---- S^T + softmax (base-2: scale and bias pre-multiplied by log2e) ----
  const float scale = 0.17677669529663687f * 1.44269504088896340f;
  f32x4 aw[2][4];
  #pragma unroll
  for (int c2 = 0; c2 < 4; ++c2)
    aw[0][c2] = *reinterpret_cast<const f32x4*>(bth + (c2 << 8) + (q << 6) + (fr << 2));
  float colsum[4] = {0.f, 0.f, 0.f, 0.f};
  unsigned pk[4][4][2];
  #pragma unroll
  for (int jf = 0; jf < 4; ++jf) {
    bf16x8 kfj;
    BUILD_FRAG(pkk, jf, kfj);
    f32x4 sacc[4];
    #pragma unroll
    for (int c2 = 0; c2 < 4; ++c2) {
      f32x4 z = {0.f, 0.f, 0.f, 0.f};
      sacc[c2] = __builtin_amdgcn_mfma_f32_16x16x32_bf16(kfj, qf[c2], z, 0, 0, 0);
    }
    if (jf < 3) {
      #pragma unroll
      for (int c2 = 0; c2 < 4; ++c2)
        aw[(jf + 1) & 1][c2] = *reinterpret_cast<const f32x4*>(
            bth + (((jf + 1) * 4 + c2) << 8) + (q << 6) + (fr << 2));
    }
    #pragma unroll
    for (int c2 = 0; c2 < 4; ++c2) {
      float ev[4];
      #pragma unroll
      for (int r = 0; r < 4; ++r) {
        float val = fmaf(sacc[c2][r], scale, aw[jf & 1][c2][r]);
        ev[r] = __builtin_amdgcn_exp2f(val);
        colsum[c2] += ev[r];
      }
      pk[jf][c2][0] = pk2(ev[0], ev[1]);
      pk[jf][c2][1] = pk2(ev[2], ev[3]);
    }
  }
  float rinv[4];
  #pragma unroll
  for (int c2 = 0; c2 < 4; ++c2) {
    float s = colsum[c2];
    s += __shfl_xor(s, 16);
    s += __shfl_xor(s, 32);
    rinv[c2] = 1.0f / s;
  }

  // ---- PV: attnT[d][i] = sum_j Vt[d][j] * P^T[j][i] (aligned b128 reads) ----
  f32x4 outT[2][4] = {};
  #pragma unroll
  for (int kb = 0; kb < 2; ++kb) {
    bf16x8 vf0 = *reinterpret_cast<const bf16x8*>(&VtW[(fr)      * VSTR + kb * 32 + q * 8]);
    bf16x8 vf1 = *reinterpret_cast<const bf16x8*>(&VtW[(16 + fr) * VSTR + kb * 32 + q * 8]);
    #pragma unroll
    for (int c2 = 0; c2 < 4; ++c2) {
      bf16x8 pf;
      {
        unsigned a0 = (unsigned)__shfl((int)pk[2 * kb][c2][0], srcA);
        unsigned a1 = (unsigned)__shfl((int)pk[2 * kb][c2][1], srcA);
        unsigned a2 = (unsigned)__shfl((int)pk[2 * kb][c2][0], srcB);
        unsigned a3 = (unsigned)__shfl((int)pk[2 * kb][c2][1], srcB);
        unsigned b0 = (unsigned)__shfl((int)pk[2 * kb + 1][c2][0], srcA);
        unsigned b1 = (unsigned)__shfl((int)pk[2 * kb + 1][c2][1], srcA);
        unsigned b2 = (unsigned)__shfl((int)pk[2 * kb + 1][c2][0], srcB);
        unsigned b3 = (unsigned)__shfl((int)pk[2 * kb + 1][c2][1], srcB);
        union { unsigned u[4]; bf16x8 v; } pfv;
        pfv.u[0] = hi ? b0 : a0;
        pfv.u[1] = hi ? b1 : a1;
        pfv.u[2] = hi ? b2 : a2;
        pfv.u[3] = hi ? b3 : a3;
        pf = pfv.v;
      }
      outT[0][c2] = __builtin_amdgcn_mfma_f32_16x16x32_bf16(vf0, pf, outT[0][c2], 0, 0, 0);
      outT[1][c2] = __builtin_amdgcn_mfma_f32_16x16x32_bf16(vf1, pf, outT[1][c2], 0, 0, 0);
    }
  }

  // ---- stage attnout in LDS (reuse x_s region rows 0-48; rows 49-63 stay zero) ----
  unsigned short* out_s = x_s;
  __syncthreads();   // all waves done reading x_s / own Vt
  #pragma unroll
  for (int c2 = 0; c2 < 4; ++c2) {
    int i = c2 * 16 + fr;
    if (i < 49) {
      float rv = rinv[c2];
      #pragma unroll
      for (int nt = 0; nt < 2; ++nt) {
        f32x4 o = outT[nt][c2];
        union { unsigned w[2]; u16x4 v; } pd;
        pd.w[0] = pk2(o[0] * rv, o[1] * rv);
        pd.w[1] = pk2(o[2] * rv, o[3] * rv);
        *reinterpret_cast<u16x4*>((char*)out_s + XS(i, head * 64 + nt * 32 + q * 8)) = pd.v;
      }
    }
  }
  __syncthreads();   // out_s complete (proj consumes all heads' columns)

  // ---- fused proj: D[pix][dim] = attnout(49x256) x Wproj^T slice (32 cols/head) ----
  {
    f32x4 pacc[2][4];   // [wsel][p2]
    #pragma unroll
    for (int w = 0; w < 2; ++w)
      #pragma unroll
      for (int p2 = 0; p2 < 4; ++p2)
        pacc[w][p2] = (f32x4){0.f, 0.f, 0.f, 0.f};
    #pragma unroll
    for (int ks = 0; ks < 8; ++ks) {
      const unsigned short* wb = wptab + (size_t)((((head * 8 + ks) * 2) * 64 + lane) * 8);
      bf16x8 wp0 = *reinterpret_cast<const bf16x8*>(wb);
      bf16x8 wp1 = *reinterpret_cast<const bf16x8*>(wb + 512);
      int bc = ks * 64 + q * 16;
      bf16x8 of0 = *reinterpret_cast<const bf16x8*>((const char*)out_s + XS(fr, bc));
      bf16x8 of1 = *reinterpret_cast<const bf16x8*>((const char*)out_s + XS(16 + fr, bc));
      bf16x8 of2 = *reinterpret_cast<const bf16x8*>((const char*)out_s + XS(32 + fr, bc));
      bf16x8 of3 = *reinterpret_cast<const bf16x8*>((const char*)out_s + XS(48 + fr, bc));
      pacc[0][0] = __builtin_amdgcn_mfma_f32_16x16x32_bf16(of0, wp0, pacc[0][0], 0, 0, 0);
      pacc[0][1] = __builtin_amdgcn_mfma_f32_16x16x32_bf16(of1, wp0, pacc[0][1], 0, 0, 0);
      pacc[0][2] = __builtin_amdgcn_mfma_f32_16x16x32_bf16(of2, wp0, pacc[0][2], 0, 0, 0);
      pacc[0][3] = __builtin_amdgcn_mfma_f32_16x16x32_bf16(of3, wp0, pacc[0][3], 0, 0, 0);
      pacc[1][0] = __builtin_amdgcn_mfma_f32_16x16x32_bf16(of0, wp1, pacc[1][0], 0, 0, 0);
      pacc[1][1] = __builtin_amdgcn_mfma_f32_16x16x32_bf16(of1, wp1, pacc[1][1], 0, 0, 0);
      pacc[1][2] = __builtin_amdgcn_mfma_f32_16x16x32_bf16(of2, wp1, pacc[1][2], 0, 0, 0);
      pacc[1][3] = __builtin_amdgcn_mfma_f32_16x16x32_bf16(of3, wp1, pacc[1][3], 0, 0, 0);
    }
    // bias + store: lane holds dim = head*32 + w*16 + fr, pix = p2*16 + q*4 + r
    float bb0 = bproj[head * 32 + fr];
    float bb1 = bproj[head * 32 + 16 + fr];
    #pragma unroll
    for (int p2 = 0; p2 < 4; ++p2) {
      #pragma unroll
      for (int r = 0; r < 4; ++r) {
        int pix = p2 * 16 + q * 4 + r;
        if (pix < 49) {
          float* op = out + (size_t)pix_s[pix] * CDIM + head * 32 + fr;
          __builtin_nontemporal_store(pacc[0][p2][r] + bb0, op);
          __builtin_nontemporal_store(pacc[1][p2][r] + bb1, op + 16);
        }
      }
    }
  }
  #undef PACK_MAT
  #undef BUILD_FRAG
  #undef XF_READS
  #undef XS
}

// ---------------- launch ----------------
extern "C" void kernel_launch(void* const* d_in, const int* in_sizes, int n_in,
                              void* d_out, int out_size, void* d_ws, size_t ws_size,
                              hipStream_t stream) {
  const float* x      = (const float*)d_in[0];
  const float* qkv_w  = (const float*)d_in[1];
  const float* qkv_b  = (const float*)d_in[2];
  const float* proj_w = (const float*)d_in[3];
  const float* proj_b = (const float*)d_in[4];
  const float* table  = (const float*)d_in[5];

  char* ws = (char*)d_ws;
  float*          btab  = (float*)ws;                        // 524,288 B
  unsigned short* wtab  = (unsigned short*)(ws + 524288);    // 393,216 B
  unsigned short* wptab = (unsigned short*)(ws + 917504);    // 131,072 B

  prep_kernel<<<640, 256, 0, stream>>>(table, btab, qkv_w, wtab, proj_w, wptab);

  fused_attn<<<2048, 512, 0, stream>>>(x, wtab, qkv_b, btab, wptab, proj_b,
                                       (float*)d_out);
}

// Round 25
// 125.853 us; speedup vs baseline: 2.1047x; 1.0000x over previous
//
#include <hip/hip_runtime.h>
#include <hip/hip_bf16.h>
#include <stdint.h>

typedef __attribute__((ext_vector_type(4))) float f32x4;
typedef __attribute__((ext_vector_type(8))) short bf16x8;
typedef __attribute__((ext_vector_type(8))) unsigned short u16x8;
typedef __attribute__((ext_vector_type(4))) unsigned short u16x4;

#define NPIX 100352      // 32*56*56
#define CDIM 256
#define QKVN 768
#define HWDIM 56
#define VSTR 72          // Vt row stride (elements); 144 B = 16B-aligned rows

__device__ __forceinline__ unsigned short f2bf(float f) {
  union { float f; unsigned int u; } cv; cv.f = f;
  unsigned int u = cv.u;
  unsigned int r = (u + 0x7FFFu + ((u >> 16) & 1u)) >> 16;
  return (unsigned short)r;
}
__device__ __forceinline__ float bf2f(unsigned short h) {
  union { unsigned int u; float f; } cv; cv.u = ((unsigned int)h) << 16;
  return cv.f;
}
// packed pair convert via official intrinsic (compiler emits v_cvt_pk_bf16_f32)
__device__ __forceinline__ unsigned pk2(float lo, float hi) {
  float2 a; a.x = lo; a.y = hi;
  __hip_bfloat162 h = __float22bfloat162_rn(a);
  union { __hip_bfloat162 h; unsigned u; } cv; cv.h = h;
  return cv.u;
}

// ---------------- merged prep: bias table (f32*log2e) + Wqkv + Wproj fragment tables ----------------
// blocks 0..511: bias_pre | 512..607: wqkv_pre | 608..639: wproj_pre
__global__ __launch_bounds__(256) void prep_kernel(
    const float* __restrict__ table, float* __restrict__ bt,
    const float* __restrict__ wq, unsigned short* __restrict__ wtab,
    const float* __restrict__ wp, unsigned short* __restrict__ wptab)
{
  const int bid = blockIdx.x;
  if (bid < 512) {
    int e = bid * 256 + threadIdx.x;             // 131072 total
    int r  = e & 3;
    int fr = (e >> 2) & 15;
    int q  = (e >> 6) & 3;
    int c2 = (e >> 8) & 3;
    int jf = (e >> 10) & 3;
    int h  = (e >> 12) & 7;
    int cls = (e >> 15) & 3;
    int j = jf * 16 + q * 4 + r;
    int i = c2 * 16 + fr;
    float v;
    if (j > 48 || i > 48) {
      v = -1e30f;
    } else {
      int bh = cls >> 1, bw = cls & 1;
      int iwi = i / 7, iwj = i % 7;
      int jwi = j / 7, jwj = j % 7;
      int ireg = (bh ? ((iwi < 4) ? 1 : 2) : 0) * 3 + (bw ? ((iwj < 4) ? 1 : 2) : 0);
      int jreg = (bh ? ((jwi < 4) ? 1 : 2) : 0) * 3 + (bw ? ((jwj < 4) ? 1 : 2) : 0);
      float m = (ireg == jreg) ? 0.f : -100.f;
      v = (table[((iwi - jwi + 6) * 13 + (iwj - jwj + 6)) * 8 + h] + m) * 1.44269504088896340f;
    }
    bt[e] = v;
  } else if (bid < 608) {
    int e8 = (bid - 512) * 256 + threadIdx.x;    // 24576 total
    int l = e8 & 63;
    int t1 = e8 >> 6;
    int wsel = t1 & 1;
    int ks = (t1 >> 1) & 7;
    int h = (t1 >> 4) & 7;
    int m = t1 >> 7;          // 0..2
    int row = m * 256 + h * 32 + wsel * 16 + (l & 15);
    int col = ks * 32 + (l >> 4) * 8;
    const float4* src = reinterpret_cast<const float4*>(wq + (size_t)row * 256 + col);
    float4 a = src[0], b = src[1];
    u16x8 r;
    r[0] = f2bf(a.x); r[1] = f2bf(a.y); r[2] = f2bf(a.z); r[3] = f2bf(a.w);
    r[4] = f2bf(b.x); r[5] = f2bf(b.y); r[6] = f2bf(b.z); r[7] = f2bf(b.w);
    *reinterpret_cast<u16x8*>(wtab + (size_t)e8 * 8) = r;
  } else {
    int e8 = (bid - 608) * 256 + threadIdx.x;    // 8192 total
    int l = e8 & 63;
    int t1 = e8 >> 6;
    int wsel = t1 & 1;
    int ks = (t1 >> 1) & 7;
    int h = (t1 >> 4) & 7;
    int row = h * 32 + wsel * 16 + (l & 15);
    int col = ks * 32 + (l >> 4) * 8;
    const float4* src = reinterpret_cast<const float4*>(wp + (size_t)row * 256 + col);
    float4 a = src[0], b = src[1];
    u16x8 r;
    r[0] = f2bf(a.x); r[1] = f2bf(a.y); r[2] = f2bf(a.z); r[3] = f2bf(a.w);
    r[4] = f2bf(b.x); r[5] = f2bf(b.y); r[6] = f2bf(b.z); r[7] = f2bf(b.w);
    *reinterpret_cast<u16x8*>(wptab + (size_t)e8 * 8) = r;
  }
}

// ---------------- fully fused: QKV GEMM + shifted-window attention + proj GEMM ----------------
// block = window (512 threads, 8 waves = 8 heads); 2 blocks/CU (LDS-limited)
__global__ __launch_bounds__(512, 2) void fused_attn(
    const float* __restrict__ x,              // [NPIX][256] fp32, pixel order
    const unsigned short* __restrict__ wtab,  // fragment-ordered Wqkv bf16
    const float* __restrict__ bqkv,           // [768]
    const float* __restrict__ btab,           // [4][8][4096] f32 (bias+mask)*log2e
    const unsigned short* __restrict__ wptab, // fragment-ordered Wproj bf16
    const float* __restrict__ bproj,          // [256]
    float* __restrict__ out)                  // [NPIX][256] fp32, pixel order
{
  const int win = blockIdx.x;
  const int b = win >> 6;
  const int gi = (win >> 3) & 7;
  const int gj = win & 7;
  const int t = threadIdx.x;
  const int head = t >> 6;
  const int lane = t & 63;
  const int fr = lane & 15;
  const int q = lane >> 4;

  __shared__ unsigned short x_s[64 * 256];     // x window bf16, rows 49-63 ZERO; reused as out_s
  __shared__ unsigned short Vt[8][32 * VSTR];  // per head Vt[d][j], 16B-aligned rows
  __shared__ int pix_s[64];

  // pix map for proj (covered by the staging barrier below)
  if (t < 64) {
    int idx = (t < 49) ? t : 48;
    int wi = idx / 7, wj = idx - (idx / 7) * 7;
    int ph = gi * 7 + wi + 3; if (ph >= HWDIM) ph -= HWDIM;
    int pw = gj * 7 + wj + 3; if (pw >= HWDIM) pw -= HWDIM;
    pix_s[t] = (b * HWDIM + ph) * HWDIM + pw;
  }

  // byte offset into x_s/out_s for (row, bytecol): XOR swizzle -> ~2-way banks
  #define XS(row, bc) ((unsigned)((row) * 512 + (((bc)) ^ (((row) & 7) << 4))))

  // ---- stage x window -> LDS bf16 (rows 49-63 zeroed; 4 uniform iterations) ----
  #pragma unroll
  for (int k = 0; k < 4; ++k) {
    int u = t + 512 * k;
    int pix = u >> 5, seg = u & 31;
    union { unsigned w[4]; u16x8 v; } r;
    if (pix < 49) {
      int wi = pix / 7, wj = pix - (pix / 7) * 7;
      int ph = gi * 7 + wi + 3; if (ph >= HWDIM) ph -= HWDIM;
      int pw = gj * 7 + wj + 3; if (pw >= HWDIM) pw -= HWDIM;
      int pabs = (b * HWDIM + ph) * HWDIM + pw;
      const f32x4* src = reinterpret_cast<const f32x4*>(x + (size_t)pabs * CDIM + seg * 8);
      f32x4 a = __builtin_nontemporal_load(src);
      f32x4 c = __builtin_nontemporal_load(src + 1);
      r.w[0] = pk2(a[0], a[1]); r.w[1] = pk2(a[2], a[3]);
      r.w[2] = pk2(c[0], c[1]); r.w[3] = pk2(c[2], c[3]);
    } else {
      r.w[0] = 0u; r.w[1] = 0u; r.w[2] = 0u; r.w[3] = 0u;
    }
    *reinterpret_cast<u16x8*>((char*)x_s + XS(pix, seg * 16)) = r.v;
  }
  __syncthreads();   // covers x_s AND pix_s

  const int cls = (((gi == 7) ? 1 : 0) << 1) | ((gj == 7) ? 1 : 0);
  const float* bth = btab + (((cls << 3) | head) << 12);
  unsigned short* VtW = Vt[head];
  const int srcA = ((q & 1) << 5) + fr;
  const int srcB = srcA + 16;
  const bool hi = (q >= 2);

  #define PACK_MAT(accm, pkm)                                                          \
  { _Pragma("unroll") for (int d = 0; d < 2; ++d)                                      \
      _Pragma("unroll") for (int p2 = 0; p2 < 4; ++p2) {                               \
        pkm[d][p2][0] = pk2(accm[d][p2][0], accm[d][p2][1]);                           \
        pkm[d][p2][1] = pk2(accm[d][p2][2], accm[d][p2][3]);                           \
      } }

  #define BUILD_FRAG(pkm, p2, dst)                                                     \
  { unsigned a0 = (unsigned)__shfl((int)pkm[0][p2][0], srcA);                          \
    unsigned a1 = (unsigned)__shfl((int)pkm[0][p2][1], srcA);                          \
    unsigned a2 = (unsigned)__shfl((int)pkm[0][p2][0], srcB);                          \
    unsigned a3 = (unsigned)__shfl((int)pkm[0][p2][1], srcB);                          \
    unsigned b0 = (unsigned)__shfl((int)pkm[1][p2][0], srcA);                          \
    unsigned b1 = (unsigned)__shfl((int)pkm[1][p2][1], srcA);                          \
    unsigned b2 = (unsigned)__shfl((int)pkm[1][p2][0], srcB);                          \
    unsigned b3 = (unsigned)__shfl((int)pkm[1][p2][1], srcB);                          \
    union { unsigned u[4]; bf16x8 v; } uf;                                             \
    uf.u[0] = hi ? b0 : a0; uf.u[1] = hi ? b1 : a1;                                    \
    uf.u[2] = hi ? b2 : a2; uf.u[3] = hi ? b3 : a3;                                    \
    dst = uf.v; }

  #define XF_READS                                                                     \
    int bc = ks * 64 + q * 16;                                                         \
    bf16x8 xf0 = *reinterpret_cast<const bf16x8*>((const char*)x_s + XS(fr, bc));      \
    bf16x8 xf1 = *reinterpret_cast<const bf16x8*>((const char*)x_s + XS(16 + fr, bc)); \
    bf16x8 xf2 = *reinterpret_cast<const bf16x8*>((const char*)x_s + XS(32 + fr, bc)); \
    bf16x8 xf3 = *reinterpret_cast<const bf16x8*>((const char*)x_s + XS(48 + fr, bc));

  unsigned pkk[2][4][2], pkq[2][4][2];

  // ---- pass V: compute V, scatter to Vt (acc dies into LDS) ----
  {
    f32x4 acc[2][4];
    #pragma unroll
    for (int d = 0; d < 2; ++d)
      #pragma unroll
      for (int p2 = 0; p2 < 4; ++p2)
        acc[d][p2] = (f32x4){0.f, 0.f, 0.f, 0.f};
    #pragma unroll
    for (int ks = 0; ks < 8; ++ks) {
      const unsigned short* wb = wtab + (size_t)((((2 * 8 + head) * 8 + ks) * 128 + lane) * 8);
      bf16x8 wf0 = *reinterpret_cast<const bf16x8*>(wb);
      bf16x8 wf1 = *reinterpret_cast<const bf16x8*>(wb + 512);
      XF_READS
      acc[0][0] = __builtin_amdgcn_mfma_f32_16x16x32_bf16(wf0, xf0, acc[0][0], 0, 0, 0);
      acc[0][1] = __builtin_amdgcn_mfma_f32_16x16x32_bf16(wf0, xf1, acc[0][1], 0, 0, 0);
      acc[0][2] = __builtin_amdgcn_mfma_f32_16x16x32_bf16(wf0, xf2, acc[0][2], 0, 0, 0);
      acc[0][3] = __builtin_amdgcn_mfma_f32_16x16x32_bf16(wf0, xf3, acc[0][3], 0, 0, 0);
      acc[1][0] = __builtin_amdgcn_mfma_f32_16x16x32_bf16(wf1, xf0, acc[1][0], 0, 0, 0);
      acc[1][1] = __builtin_amdgcn_mfma_f32_16x16x32_bf16(wf1, xf1, acc[1][1], 0, 0, 0);
      acc[1][2] = __builtin_amdgcn_mfma_f32_16x16x32_bf16(wf1, xf2, acc[1][2], 0, 0, 0);
      acc[1][3] = __builtin_amdgcn_mfma_f32_16x16x32_bf16(wf1, xf3, acc[1][3], 0, 0, 0);
    }
    #pragma unroll
    for (int d = 0; d < 2; ++d) {
      f32x4 bv = *reinterpret_cast<const f32x4*>(bqkv + 512 + head * 32 + d * 16 + q * 4);
      #pragma unroll
      for (int p2 = 0; p2 < 4; ++p2) {
        f32x4 v = acc[d][p2] + bv;
        #pragma unroll
        for (int r = 0; r < 4; ++r)
          VtW[(d * 16 + q * 4 + r) * VSTR + p2 * 16 + fr] = f2bf(v[r]);
      }
    }
  }

  // ---- pass K+Q fused: one xf read feeds both weight sets ----
  {
    f32x4 acck[2][4], accq[2][4];
    #pragma unroll
    for (int d = 0; d < 2; ++d)
      #pragma unroll
      for (int p2 = 0; p2 < 4; ++p2) {
        acck[d][p2] = (f32x4){0.f, 0.f, 0.f, 0.f};
        accq[d][p2] = (f32x4){0.f, 0.f, 0.f, 0.f};
      }
    #pragma unroll
    for (int ks = 0; ks < 8; ++ks) {
      const unsigned short* wbK = wtab + (size_t)((((1 * 8 + head) * 8 + ks) * 128 + lane) * 8);
      const unsigned short* wbQ = wtab + (size_t)((((0 * 8 + head) * 8 + ks) * 128 + lane) * 8);
      bf16x8 wk0 = *reinterpret_cast<const bf16x8*>(wbK);
      bf16x8 wk1 = *reinterpret_cast<const bf16x8*>(wbK + 512);
      bf16x8 wq0 = *reinterpret_cast<const bf16x8*>(wbQ);
      bf16x8 wq1 = *reinterpret_cast<const bf16x8*>(wbQ + 512);
      XF_READS
      acck[0][0] = __builtin_amdgcn_mfma_f32_16x16x32_bf16(wk0, xf0, acck[0][0], 0, 0, 0);
      acck[0][1] = __builtin_amdgcn_mfma_f32_16x16x32_bf16(wk0, xf1, acck[0][1], 0, 0, 0);
      acck[0][2] = __builtin_amdgcn_mfma_f32_16x16x32_bf16(wk0, xf2, acck[0][2], 0, 0, 0);
      acck[0][3] = __builtin_amdgcn_mfma_f32_16x16x32_bf16(wk0, xf3, acck[0][3], 0, 0, 0);
      acck[1][0] = __builtin_amdgcn_mfma_f32_16x16x32_bf16(wk1, xf0, acck[1][0], 0, 0, 0);
      acck[1][1] = __builtin_amdgcn_mfma_f32_16x16x32_bf16(wk1, xf1, acck[1][1], 0, 0, 0);
      acck[1][2] = __builtin_amdgcn_mfma_f32_16x16x32_bf16(wk1, xf2, acck[1][2], 0, 0, 0);
      acck[1][3] = __builtin_amdgcn_mfma_f32_16x16x32_bf16(wk1, xf3, acck[1][3], 0, 0, 0);
      accq[0][0] = __builtin_amdgcn_mfma_f32_16x16x32_bf16(wq0, xf0, accq[0][0], 0, 0, 0);
      accq[0][1] = __builtin_amdgcn_mfma_f32_16x16x32_bf16(wq0, xf1, accq[0][1], 0, 0, 0);
      accq[0][2] = __builtin_amdgcn_mfma_f32_16x16x32_bf16(wq0, xf2, accq[0][2], 0, 0, 0);
      accq[0][3] = __builtin_amdgcn_mfma_f32_16x16x32_bf16(wq0, xf3, accq[0][3], 0, 0, 0);
      accq[1][0] = __builtin_amdgcn_mfma_f32_16x16x32_bf16(wq1, xf0, accq[1][0], 0, 0, 0);
      accq[1][1] = __builtin_amdgcn_mfma_f32_16x16x32_bf16(wq1, xf1, accq[1][1], 0, 0, 0);
      accq[1][2] = __builtin_amdgcn_mfma_f32_16x16x32_bf16(wq1, xf2, accq[1][2], 0, 0, 0);
      accq[1][3] = __builtin_amdgcn_mfma_f32_16x16x32_bf16(wq1, xf3, accq[1][3], 0, 0, 0);
    }
    const float sc = 0.17677669529663687f * 1.44269504088896340f;  // scale*log2e into Q
    #pragma unroll
    for (int d = 0; d < 2; ++d) {
      f32x4 bvk = *reinterpret_cast<const f32x4*>(bqkv + 256 + head * 32 + d * 16 + q * 4);
      f32x4 bvq = *reinterpret_cast<const f32x4*>(bqkv +       head * 32 + d * 16 + q * 4);
      #pragma unroll
      for (int p2 = 0; p2 < 4; ++p2) {
        acck[d][p2] += bvk;
        accq[d][p2] = (accq[d][p2] + bvq) * sc;
      }
    }
    PACK_MAT(acck, pkk);
    PACK_MAT(accq, pkq);
  }

  bf16x8 qf[4];
  BUILD_FRAG(pkq, 0, qf[0]); BUILD_FRAG(pkq, 1, qf[1]);
  BUILD_FRAG(pkq, 2, qf[2]); BUILD_FRAG(pkq, 3, qf[3]);

  // ---- S^T + softmax: bias rides MFMA C-operand; Q pre-scaled ----
  f32x4 aw[2][4];
  #pragma unroll
  for (int c2 = 0; c2 < 4; ++c2)
    aw[0][c2] = *reinterpret_cast<const f32x4*>(bth + (c2 << 8) + (q << 6) + (fr << 2));
  float colsum[4] = {0.f, 0.f, 0.f, 0.f};
  unsigned pk[4][4][2];
  #pragma unroll
  for (int jf = 0; jf < 4; ++jf) {
    bf16x8 kfj;
    BUILD_FRAG(pkk, jf, kfj);
    f32x4 sacc[4];
    #pragma unroll
    for (int c2 = 0; c2 < 4; ++c2)
      sacc[c2] = __builtin_amdgcn_mfma_f32_16x16x32_bf16(kfj, qf[c2], aw[jf & 1][c2], 0, 0, 0);
    if (jf < 3) {
      #pragma unroll
      for (int c2 = 0; c2 < 4; ++c2)
        aw[(jf + 1) & 1][c2] = *reinterpret_cast<const f32x4*>(
            bth + (((jf + 1) * 4 + c2) << 8) + (q << 6) + (fr << 2));
    }
    #pragma unroll
    for (int c2 = 0; c2 < 4; ++c2) {
      float ev[4];
      #pragma unroll
      for (int r = 0; r < 4; ++r) {
        ev[r] = __builtin_amdgcn_exp2f(sacc[c2][r]);
        colsum[c2] += ev[r];
      }
      pk[jf][c2][0] = pk2(ev[0], ev[1]);
      pk[jf][c2][1] = pk2(ev[2], ev[3]);
    }
  }
  float rinv[4];
  #pragma unroll
  for (int c2 = 0; c2 < 4; ++c2) {
    float s = colsum[c2];
    s += __shfl_xor(s, 16);
    s += __shfl_xor(s, 32);
    rinv[c2] = 1.0f / s;
  }

  // ---- PV: attnT[d][i] = sum_j Vt[d][j] * P^T[j][i] (aligned b128 reads) ----
  f32x4 outT[2][4] = {};
  #pragma unroll
  for (int kb = 0; kb < 2; ++kb) {
    bf16x8 vf0 = *reinterpret_cast<const bf16x8*>(&VtW[(fr)      * VSTR + kb * 32 + q * 8]);
    bf16x8 vf1 = *reinterpret_cast<const bf16x8*>(&VtW[(16 + fr) * VSTR + kb * 32 + q * 8]);
    #pragma unroll
    for (int c2 = 0; c2 < 4; ++c2) {
      bf16x8 pf;
      {
        unsigned a0 = (unsigned)__shfl((int)pk[2 * kb][c2][0], srcA);
        unsigned a1 = (unsigned)__shfl((int)pk[2 * kb][c2][1], srcA);
        unsigned a2 = (unsigned)__shfl((int)pk[2 * kb][c2][0], srcB);
        unsigned a3 = (unsigned)__shfl((int)pk[2 * kb][c2][1], srcB);
        unsigned b0 = (unsigned)__shfl((int)pk[2 * kb + 1][c2][0], srcA);
        unsigned b1 = (unsigned)__shfl((int)pk[2 * kb + 1][c2][1], srcA);
        unsigned b2 = (unsigned)__shfl((int)pk[2 * kb + 1][c2][0], srcB);
        unsigned b3 = (unsigned)__shfl((int)pk[2 * kb + 1][c2][1], srcB);
        union { unsigned u[4]; bf16x8 v; } pfv;
        pfv.u[0] = hi ? b0 : a0;
        pfv.u[1] = hi ? b1 : a1;
        pfv.u[2] = hi ? b2 : a2;
        pfv.u[3] = hi ? b3 : a3;
        pf = pfv.v;
      }
      outT[0][c2] = __builtin_amdgcn_mfma_f32_16x16x32_bf16(vf0, pf, outT[0][c2], 0, 0, 0);
      outT[1][c2] = __builtin_amdgcn_mfma_f32_16x16x32_bf16(vf1, pf, outT[1][c2], 0, 0, 0);
    }
  }

  // ---- stage attnout in LDS (reuse x_s region rows 0-48; rows 49-63 stay zero) ----
  unsigned short* out_s = x_s;
  __syncthreads();   // all waves done reading x_s / own Vt
  #pragma unroll
  for (int c2 = 0; c2 < 4; ++c2) {
    int i = c2 * 16 + fr;
    if (i < 49) {
      float rv = rinv[c2];
      #pragma unroll
      for (int nt = 0; nt < 2; ++nt) {
        f32x4 o = outT[nt][c2];
        union { unsigned w[2]; u16x4 v; } pd;
        pd.w[0] = pk2(o[0] * rv, o[1] * rv);
        pd.w[1] = pk2(o[2] * rv, o[3] * rv);
        *reinterpret_cast<u16x4*>((char*)out_s + XS(i, head * 64 + nt * 32 + q * 8)) = pd.v;
      }
    }
  }
  __syncthreads();   // out_s complete (proj consumes all heads' columns)

  // ---- fused proj: D[pix][dim] = attnout(49x256) x Wproj^T slice (32 cols/head) ----
  {
    f32x4 pacc[2][4];   // [wsel][p2]
    #pragma unroll
    for (int w = 0; w < 2; ++w)
      #pragma unroll
      for (int p2 = 0; p2 < 4; ++p2)
        pacc[w][p2] = (f32x4){0.f, 0.f, 0.f, 0.f};
    #pragma unroll
    for (int ks = 0; ks < 8; ++ks) {
      const unsigned short* wb = wptab + (size_t)((((head * 8 + ks) * 2) * 64 + lane) * 8);
      bf16x8 wp0 = *reinterpret_cast<const bf16x8*>(wb);
      bf16x8 wp1 = *reinterpret_cast<const bf16x8*>(wb + 512);
      int bc = ks * 64 + q * 16;
      bf16x8 of0 = *reinterpret_cast<const bf16x8*>((const char*)out_s + XS(fr, bc));
      bf16x8 of1 = *reinterpret_cast<const bf16x8*>((const char*)out_s + XS(16 + fr, bc));
      bf16x8 of2 = *reinterpret_cast<const bf16x8*>((const char*)out_s + XS(32 + fr, bc));
      bf16x8 of3 = *reinterpret_cast<const bf16x8*>((const char*)out_s + XS(48 + fr, bc));
      pacc[0][0] = __builtin_amdgcn_mfma_f32_16x16x32_bf16(of0, wp0, pacc[0][0], 0, 0, 0);
      pacc[0][1] = __builtin_amdgcn_mfma_f32_16x16x32_bf16(of1, wp0, pacc[0][1], 0, 0, 0);
      pacc[0][2] = __builtin_amdgcn_mfma_f32_16x16x32_bf16(of2, wp0, pacc[0][2], 0, 0, 0);
      pacc[0][3] = __builtin_amdgcn_mfma_f32_16x16x32_bf16(of3, wp0, pacc[0][3], 0, 0, 0);
      pacc[1][0] = __builtin_amdgcn_mfma_f32_16x16x32_bf16(of0, wp1, pacc[1][0], 0, 0, 0);
      pacc[1][1] = __builtin_amdgcn_mfma_f32_16x16x32_bf16(of1, wp1, pacc[1][1], 0, 0, 0);
      pacc[1][2] = __builtin_amdgcn_mfma_f32_16x16x32_bf16(of2, wp1, pacc[1][2], 0, 0, 0);
      pacc[1][3] = __builtin_amdgcn_mfma_f32_16x16x32_bf16(of3, wp1, pacc[1][3], 0, 0, 0);
    }
    // bias + store: lane holds dim = head*32 + w*16 + fr, pix = p2*16 + q*4 + r
    float bb0 = bproj[head * 32 + fr];
    float bb1 = bproj[head * 32 + 16 + fr];
    #pragma unroll
    for (int p2 = 0; p2 < 4; ++p2) {
      #pragma unroll
      for (int r = 0; r < 4; ++r) {
        int pix = p2 * 16 + q * 4 + r;
        if (pix < 49) {
          float* op = out + (size_t)pix_s[pix] * CDIM + head * 32 + fr;
          __builtin_nontemporal_store(pacc[0][p2][r] + bb0, op);
          __builtin_nontemporal_store(pacc[1][p2][r] + bb1, op + 16);
        }
      }
    }
  }
  #undef PACK_MAT
  #undef BUILD_FRAG
  #undef XF_READS
  #undef XS
}

// ---------------- launch ----------------
extern "C" void kernel_launch(void* const* d_in, const int* in_sizes, int n_in,
                              void* d_out, int out_size, void* d_ws, size_t ws_size,
                              hipStream_t stream) {
  const float* x      = (const float*)d_in[0];
  const float* qkv_w  = (const float*)d_in[1];
  const float* qkv_b  = (const float*)d_in[2];
  const float* proj_w = (const float*)d_in[3];
  const float* proj_b = (const float*)d_in[4];
  const float* table  = (const float*)d_in[5];

  char* ws = (char*)d_ws;
  float*          btab  = (float*)ws;                        // 524,288 B
  unsigned short* wtab  = (unsigned short*)(ws + 524288);    // 393,216 B
  unsigned short* wptab = (unsigned short*)(ws + 917504);    // 131,072 B

  prep_kernel<<<640, 256, 0, stream>>>(table, btab, qkv_w, wtab, proj_w, wptab);

  fused_attn<<<2048, 512, 0, stream>>>(x, wtab, qkv_b, btab, wptab, proj_b,
                                       (float*)d_out);
}